// Round 2
// baseline (1036.827 us; speedup 1.0000x reference)
//
#include <hip/hip_runtime.h>
#include <hip/hip_bf16.h>

typedef __hip_bfloat16 bf16;

// ---------- constants ----------
// B=2, N=2048, C=128, H=8, hd=16, branches=3, hid=768
// rows per branch = B*N = 4096; 3C = 384
// I/O is fp32 (reference dtype); intermediates bf16 except xc (fp32 residual).

static __device__ __forceinline__ float b2f(bf16 h) { return __bfloat162float(h); }
static __device__ __forceinline__ bf16 f2b(float f) { return __float2bfloat16(f); }

// ================= K1: LN1 for all 3 branches =================
// one wave per row (128 cols, 2 per lane); 12288 rows total
__global__ __launch_bounds__(256) void k_ln1(const float* __restrict__ x1, const float* __restrict__ x2,
                                             const float* __restrict__ x3, const float* __restrict__ g,
                                             const float* __restrict__ b, bf16* __restrict__ xn) {
    int tid = threadIdx.x;
    int wave = tid >> 6, lane = tid & 63;
    int grow = blockIdx.x * 4 + wave;      // 0..12287
    int branch = grow >> 12;               // /4096
    const float* xp = (branch == 0) ? x1 : (branch == 1 ? x2 : x3);
    const float* row = xp + (size_t)(grow & 4095) * 128;
    float2 a = *reinterpret_cast<const float2*>(&row[2 * lane]);
    float s = a.x + a.y, sq = a.x * a.x + a.y * a.y;
#pragma unroll
    for (int off = 32; off >= 1; off >>= 1) { s += __shfl_xor(s, off); sq += __shfl_xor(sq, off); }
    float mean = s * (1.f / 128.f);
    float var = sq * (1.f / 128.f) - mean * mean;
    float rstd = rsqrtf(var + 1e-5f);
    float2 gv = *reinterpret_cast<const float2*>(&g[branch * 128 + 2 * lane]);
    float2 bv = *reinterpret_cast<const float2*>(&b[branch * 128 + 2 * lane]);
    bf16* orow = xn + (size_t)grow * 128;
    orow[2 * lane] = f2b((a.x - mean) * rstd * gv.x + bv.x);
    orow[2 * lane + 1] = f2b((a.y - mean) * rstd * gv.y + bv.y);
}

// ================= K2: QKV GEMM [4096x384x128] per branch, scatter to q/k/v =================
// block 384 threads: thread owns output column c; 32 rows per block staged in LDS (fp32)
__global__ __launch_bounds__(384) void k_qkv(const bf16* __restrict__ xn, const float* __restrict__ w,
                                             bf16* __restrict__ q, bf16* __restrict__ k, bf16* __restrict__ v) {
    __shared__ float xl[32][128];
    int branch = blockIdx.x, rb = blockIdx.y;
    int tid = threadIdx.x;
    const bf16* xbase = xn + ((size_t)branch * 4096 + rb * 32) * 128;
    for (int i = tid; i < 32 * 128; i += 384) xl[i >> 7][i & 127] = b2f(xbase[i]);
    __syncthreads();
    int c = tid;  // 0..383
    const float* wc = w + (size_t)branch * 128 * 384 + c;
    float acc[32];
#pragma unroll
    for (int r = 0; r < 32; ++r) acc[r] = 0.f;
    for (int k0 = 0; k0 < 128; k0 += 4) {
        float w0 = wc[(k0 + 0) * 384];
        float w1 = wc[(k0 + 1) * 384];
        float w2 = wc[(k0 + 2) * 384];
        float w3 = wc[(k0 + 3) * 384];
#pragma unroll
        for (int r = 0; r < 32; ++r) {
            float4 xv = *reinterpret_cast<const float4*>(&xl[r][k0]);
            acc[r] += xv.x * w0 + xv.y * w1 + xv.z * w2 + xv.w * w3;
        }
    }
    int which = c >> 7, h = (c & 127) >> 4, d = c & 15;
    bf16* dst = (which == 0) ? q : (which == 1 ? k : v);
    int rowbase = rb * 32;
    for (int r = 0; r < 32; ++r) {
        int row = rowbase + r;              // row within branch = b*2048 + n
        int bb = row >> 11, n = row & 2047;
        size_t idx = ((((size_t)branch * 2 + bb) * 8 + h) * 2048 + n) * 16 + d;
        dst[idx] = f2b(acc[r]);
    }
}

// ================= K3: attention, flash-style online softmax =================
// grid (48 bh, 128 rowblocks of 16 rows); 256 threads = 4 waves, 4 rows/wave
// K chunk fp32 (swizzled), V chunk bf16 (swizzled) in LDS, 512 keys per chunk
__global__ __launch_bounds__(256) void k_attn(const bf16* __restrict__ qg, const bf16* __restrict__ kg,
                                              const bf16* __restrict__ vg, bf16* __restrict__ o) {
    __shared__ float kl[512 * 16];    // 32 KB
    __shared__ bf16 vl[512 * 16];     // 16 KB
    __shared__ float ql[16 * 16];     // 1 KB
    int bh = blockIdx.x;              // 0..47
    int rblk = blockIdx.y;            // 0..127
    int branch = bh >> 4;
    int bb = (bh >> 3) & 1;
    int h = bh & 7;
    size_t base = (((size_t)branch * 2 + bb) * 8 + h) * 2048 * 16;
    int tid = threadIdx.x, wave = tid >> 6, lane = tid & 63;
    int row0 = rblk * 16;
    for (int i = tid; i < 16 * 16; i += 256)
        ql[i] = b2f(qg[base + (size_t)(row0 + (i >> 4)) * 16 + (i & 15)]);

    float m[4], sum[4], out[4][16];
#pragma unroll
    for (int rr = 0; rr < 4; ++rr) {
        m[rr] = -INFINITY; sum[rr] = 0.f;
#pragma unroll
        for (int d = 0; d < 16; ++d) out[rr][d] = 0.f;
    }

    for (int c0 = 0; c0 < 2048; c0 += 512) {
        __syncthreads();
        // K chunk -> fp32 LDS, 16B-chunk swizzle: c' = c ^ ((j>>1)&3)
        for (int i = tid; i < 512 * 16; i += 256) {
            int jj = i >> 4, d = i & 15;
            float val = b2f(kg[base + (size_t)(c0 + jj) * 16 + d]);
            int cc = d >> 2;
            int cs = cc ^ ((jj >> 1) & 3);
            kl[jj * 16 + cs * 4 + (d & 3)] = val;
        }
        // V chunk -> bf16 LDS, 16B-chunk swizzle: c' = c ^ ((j>>2)&1)
        for (int i = tid; i < 512 * 16; i += 256) {
            int jj = i >> 4, d = i & 15;
            bf16 val = vg[base + (size_t)(c0 + jj) * 16 + d];
            int cc = d >> 3;
            int cs = cc ^ ((jj >> 2) & 1);
            vl[jj * 16 + cs * 8 + (d & 7)] = val;
        }
        __syncthreads();
#pragma unroll
        for (int rr = 0; rr < 4; ++rr) {
            int rl = wave * 4 + rr;
            float qv[16];
#pragma unroll
            for (int d4 = 0; d4 < 4; ++d4) {
                float4 t = *reinterpret_cast<const float4*>(&ql[rl * 16 + d4 * 4]);
                qv[d4 * 4 + 0] = t.x; qv[d4 * 4 + 1] = t.y;
                qv[d4 * 4 + 2] = t.z; qv[d4 * 4 + 3] = t.w;
            }
            float s[8];
            float cmax = -INFINITY;
#pragma unroll
            for (int i = 0; i < 8; ++i) {
                int jl = lane + (i << 6);
                int sw = (jl >> 1) & 3;
                float acc = 0.f;
#pragma unroll
                for (int cch = 0; cch < 4; ++cch) {
                    int cs = cch ^ sw;
                    float4 kv = *reinterpret_cast<const float4*>(&kl[jl * 16 + cs * 4]);
                    acc += qv[cch * 4 + 0] * kv.x + qv[cch * 4 + 1] * kv.y +
                           qv[cch * 4 + 2] * kv.z + qv[cch * 4 + 3] * kv.w;
                }
                s[i] = acc * 0.25f;  // scale = hd^-0.5
                cmax = fmaxf(cmax, s[i]);
            }
#pragma unroll
            for (int off = 32; off >= 1; off >>= 1) cmax = fmaxf(cmax, __shfl_xor(cmax, off));
            float mnew = fmaxf(m[rr], cmax);
            float fac = __expf(m[rr] - mnew);
            m[rr] = mnew;
            sum[rr] *= fac;
#pragma unroll
            for (int d = 0; d < 16; ++d) out[rr][d] *= fac;
#pragma unroll
            for (int i = 0; i < 8; ++i) {
                int jl = lane + (i << 6);
                float p = __expf(s[i] - mnew);
                sum[rr] += p;
                int sw = (jl >> 2) & 1;
#pragma unroll
                for (int cch = 0; cch < 2; ++cch) {
                    int cs = cch ^ sw;
                    float4 vv = *reinterpret_cast<const float4*>(&vl[jl * 16 + cs * 8]);
                    const unsigned int* u = reinterpret_cast<const unsigned int*>(&vv);
#pragma unroll
                    for (int e = 0; e < 4; ++e) {
                        float lo = __uint_as_float(u[e] << 16);
                        float hi = __uint_as_float(u[e] & 0xffff0000u);
                        out[rr][cch * 8 + e * 2] += p * lo;
                        out[rr][cch * 8 + e * 2 + 1] += p * hi;
                    }
                }
            }
        }
    }
    // final cross-lane reduce + write (avoid dynamic register indexing)
#pragma unroll
    for (int rr = 0; rr < 4; ++rr) {
        float sv = sum[rr];
#pragma unroll
        for (int off = 32; off >= 1; off >>= 1) sv += __shfl_xor(sv, off);
        float wval = 0.f;
#pragma unroll
        for (int d = 0; d < 16; ++d) {
            float ov = out[rr][d];
#pragma unroll
            for (int off = 32; off >= 1; off >>= 1) ov += __shfl_xor(ov, off);
            if (lane == d) wval = ov;
        }
        float inv = 1.f / sv;
        int n = row0 + wave * 4 + rr;
        if (lane < 16) {
            size_t orow = (size_t)branch * 4096 + (size_t)bb * 2048 + n;
            o[orow * 128 + h * 16 + lane] = f2b(wval * inv);
        }
    }
}

// ================= K4: proj GEMM [4096x128x128] + bias + residual -> xc[4096][384] fp32 =================
__global__ __launch_bounds__(128) void k_proj(const bf16* __restrict__ o, const float* __restrict__ w,
                                              const float* __restrict__ pb, const float* __restrict__ x1,
                                              const float* __restrict__ x2, const float* __restrict__ x3,
                                              float* __restrict__ xc) {
    __shared__ float ol[32][128];
    int branch = blockIdx.x, rb = blockIdx.y, tid = threadIdx.x;
    const bf16* obase = o + ((size_t)branch * 4096 + rb * 32) * 128;
    for (int i = tid; i < 32 * 128; i += 128) ol[i >> 7][i & 127] = b2f(obase[i]);
    __syncthreads();
    int c = tid;
    const float* wc = w + (size_t)branch * 128 * 128 + c;
    float acc[32];
#pragma unroll
    for (int r = 0; r < 32; ++r) acc[r] = 0.f;
    for (int k0 = 0; k0 < 128; k0 += 4) {
        float w0 = wc[(k0 + 0) * 128];
        float w1 = wc[(k0 + 1) * 128];
        float w2 = wc[(k0 + 2) * 128];
        float w3 = wc[(k0 + 3) * 128];
#pragma unroll
        for (int r = 0; r < 32; ++r) {
            float4 xv = *reinterpret_cast<const float4*>(&ol[r][k0]);
            acc[r] += xv.x * w0 + xv.y * w1 + xv.z * w2 + xv.w * w3;
        }
    }
    float bias = pb[branch * 128 + c];
    const float* xp = (branch == 0) ? x1 : (branch == 1 ? x2 : x3);
    for (int r = 0; r < 32; ++r) {
        int row = rb * 32 + r;
        float res = xp[(size_t)row * 128 + c];
        xc[(size_t)row * 384 + branch * 128 + c] = acc[r] + bias + res;
    }
}

// ================= K5: LN2 over 384 features =================
__global__ __launch_bounds__(256) void k_ln2(const float* __restrict__ xc, const float* __restrict__ g,
                                             const float* __restrict__ b, bf16* __restrict__ xcn) {
    int tid = threadIdx.x, wave = tid >> 6, lane = tid & 63;
    int row = blockIdx.x * 4 + wave;  // 0..4095
    const float* rp = xc + (size_t)row * 384;
    float v[6];
    float s = 0.f, sq = 0.f;
#pragma unroll
    for (int i = 0; i < 6; ++i) {
        v[i] = rp[lane + i * 64];
        s += v[i]; sq += v[i] * v[i];
    }
#pragma unroll
    for (int off = 32; off >= 1; off >>= 1) { s += __shfl_xor(s, off); sq += __shfl_xor(sq, off); }
    float mean = s * (1.f / 384.f);
    float var = sq * (1.f / 384.f) - mean * mean;
    float rstd = rsqrtf(var + 1e-5f);
    bf16* op = xcn + (size_t)row * 384;
#pragma unroll
    for (int i = 0; i < 6; ++i) {
        int c = lane + i * 64;
        op[c] = f2b((v[i] - mean) * rstd * g[c] + b[c]);
    }
}

// ================= K6: FC1 [4096x768x384] + bias + exact GELU =================
__global__ __launch_bounds__(256) void k_fc1(const bf16* __restrict__ xcn, const float* __restrict__ w,
                                             const float* __restrict__ bias, bf16* __restrict__ h) {
    __shared__ float xl[32][384];  // 48 KB
    int rb = blockIdx.x, cb = blockIdx.y, tid = threadIdx.x;
    const bf16* xbase = xcn + (size_t)rb * 32 * 384;
    for (int i = tid; i < 32 * 384; i += 256) {
        int r = i / 384, kk = i - r * 384;
        xl[r][kk] = b2f(xbase[i]);
    }
    __syncthreads();
    int c = cb * 256 + tid;  // 0..767
    const float* wc = w + c;
    float acc[32];
#pragma unroll
    for (int r = 0; r < 32; ++r) acc[r] = 0.f;
    for (int k0 = 0; k0 < 384; k0 += 4) {
        float w0 = wc[(size_t)(k0 + 0) * 768];
        float w1 = wc[(size_t)(k0 + 1) * 768];
        float w2 = wc[(size_t)(k0 + 2) * 768];
        float w3 = wc[(size_t)(k0 + 3) * 768];
#pragma unroll
        for (int r = 0; r < 32; ++r) {
            float4 xv = *reinterpret_cast<const float4*>(&xl[r][k0]);
            acc[r] += xv.x * w0 + xv.y * w1 + xv.z * w2 + xv.w * w3;
        }
    }
    float bs = bias[c];
    for (int r = 0; r < 32; ++r) {
        float vv = acc[r] + bs;
        float ge = 0.5f * vv * (1.f + erff(vv * 0.70710678118f));
        h[((size_t)rb * 32 + r) * 768 + c] = f2b(ge);
    }
}

// ================= K7: FC2 [4096x384x768] + bias + residual -> split fp32 outputs =================
__global__ __launch_bounds__(384) void k_fc2(const bf16* __restrict__ h, const float* __restrict__ w,
                                             const float* __restrict__ bias, const float* __restrict__ xc,
                                             float* __restrict__ outp) {
    __shared__ float hl[32][384];  // 48 KB, two K-passes of 384
    int rb = blockIdx.x, tid = threadIdx.x;
    int c = tid;  // 0..383
    float acc[32];
#pragma unroll
    for (int r = 0; r < 32; ++r) acc[r] = 0.f;
    for (int p = 0; p < 2; ++p) {
        __syncthreads();
        const bf16* hbase = h + (size_t)rb * 32 * 768 + p * 384;
        for (int t = 0; t < 32; ++t) hl[t][tid] = b2f(hbase[(size_t)t * 768 + tid]);
        __syncthreads();
        const float* wc = w + (size_t)p * 384 * 384 + c;
        for (int k0 = 0; k0 < 384; k0 += 4) {
            float w0 = wc[(size_t)(k0 + 0) * 384];
            float w1 = wc[(size_t)(k0 + 1) * 384];
            float w2 = wc[(size_t)(k0 + 2) * 384];
            float w3 = wc[(size_t)(k0 + 3) * 384];
#pragma unroll
            for (int r = 0; r < 32; ++r) {
                float4 hv = *reinterpret_cast<const float4*>(&hl[r][k0]);
                acc[r] += hv.x * w0 + hv.y * w1 + hv.z * w2 + hv.w * w3;
            }
        }
    }
    float bs = bias[c];
    int which = c >> 7, cc = c & 127;
    for (int r = 0; r < 32; ++r) {
        size_t row = (size_t)rb * 32 + r;
        float res = xc[row * 384 + c];
        outp[(size_t)which * 524288 + row * 128 + cc] = acc[r] + bs + res;
    }
}

// ================= launch =================
extern "C" void kernel_launch(void* const* d_in, const int* in_sizes, int n_in,
                              void* d_out, int out_size, void* d_ws, size_t ws_size,
                              hipStream_t stream) {
    const float* x1     = (const float*)d_in[0];
    const float* x2     = (const float*)d_in[1];
    const float* x3     = (const float*)d_in[2];
    const float* ln1_g  = (const float*)d_in[3];
    const float* ln1_b  = (const float*)d_in[4];
    const float* qkv_w  = (const float*)d_in[5];
    const float* proj_w = (const float*)d_in[6];
    const float* proj_b = (const float*)d_in[7];
    const float* ln2_g  = (const float*)d_in[8];
    const float* ln2_b  = (const float*)d_in[9];
    const float* fc1_w  = (const float*)d_in[10];
    const float* fc1_b  = (const float*)d_in[11];
    const float* fc2_w  = (const float*)d_in[12];
    const float* fc2_b  = (const float*)d_in[13];

    char* ws = (char*)d_ws;
    const size_t SB = 3145728;  // 3*4096*128*2 bytes (bf16 buffer of 1.5M elems)
    bf16* xn  = (bf16*)(ws + 0 * SB);
    bf16* qb  = (bf16*)(ws + 1 * SB);
    bf16* kb  = (bf16*)(ws + 2 * SB);
    bf16* vb  = (bf16*)(ws + 3 * SB);
    bf16* ob  = (bf16*)(ws + 4 * SB);
    float* xc = (float*)(ws + 5 * SB);            // 4096*384*4 = 6291456 B
    bf16* xcn = (bf16*)(ws + 5 * SB + 6291456);   // 3145728 B
    bf16* hb  = (bf16*)(ws + 6 * SB + 6291456);   // 4096*768*2 = 6291456 B
    // total = 5*3145728 + 6291456 + 3145728 + 6291456 = 31457280 B (30 MB)

    k_ln1<<<3072, 256, 0, stream>>>(x1, x2, x3, ln1_g, ln1_b, xn);
    k_qkv<<<dim3(3, 128), 384, 0, stream>>>(xn, qkv_w, qb, kb, vb);
    k_attn<<<dim3(48, 128), 256, 0, stream>>>(qb, kb, vb, ob);
    k_proj<<<dim3(3, 128), 128, 0, stream>>>(ob, proj_w, proj_b, x1, x2, x3, xc);
    k_ln2<<<1024, 256, 0, stream>>>(xc, ln2_g, ln2_b, xcn);
    k_fc1<<<dim3(128, 3), 256, 0, stream>>>(xcn, fc1_w, fc1_b, hb);
    k_fc2<<<128, 384, 0, stream>>>(hb, fc2_w, fc2_b, xc, (float*)d_out);
}

// Round 3
// 425.005 us; speedup vs baseline: 2.4396x; 2.4396x over previous
//
#include <hip/hip_runtime.h>
#include <hip/hip_bf16.h>

typedef __hip_bfloat16 bf16;

// ---------- constants ----------
// B=2, N=2048, C=128, H=8, hd=16, branches=3, hid=768
// rows per branch = B*N = 4096; 3C = 384
// I/O is fp32 (reference dtype); intermediates bf16 except xc (fp32 residual).

static __device__ __forceinline__ float b2f(bf16 h) { return __bfloat162float(h); }
static __device__ __forceinline__ bf16 f2b(float f) { return __float2bfloat16(f); }
static __device__ __forceinline__ unsigned short f2bu(float f) {
    bf16 h = f2b(f);
    return *reinterpret_cast<unsigned short*>(&h);
}

typedef __attribute__((ext_vector_type(8))) short short8;
typedef __attribute__((ext_vector_type(4))) short short4v;
typedef __attribute__((ext_vector_type(16))) float f32x16;
typedef __attribute__((ext_vector_type(2))) int int2v;

// ================= K1: LN1 for all 3 branches =================
__global__ __launch_bounds__(256) void k_ln1(const float* __restrict__ x1, const float* __restrict__ x2,
                                             const float* __restrict__ x3, const float* __restrict__ g,
                                             const float* __restrict__ b, bf16* __restrict__ xn) {
    int tid = threadIdx.x;
    int wave = tid >> 6, lane = tid & 63;
    int grow = blockIdx.x * 4 + wave;      // 0..12287
    int branch = grow >> 12;               // /4096
    const float* xp = (branch == 0) ? x1 : (branch == 1 ? x2 : x3);
    const float* row = xp + (size_t)(grow & 4095) * 128;
    float2 a = *reinterpret_cast<const float2*>(&row[2 * lane]);
    float s = a.x + a.y, sq = a.x * a.x + a.y * a.y;
#pragma unroll
    for (int off = 32; off >= 1; off >>= 1) { s += __shfl_xor(s, off); sq += __shfl_xor(sq, off); }
    float mean = s * (1.f / 128.f);
    float var = sq * (1.f / 128.f) - mean * mean;
    float rstd = rsqrtf(var + 1e-5f);
    float2 gv = *reinterpret_cast<const float2*>(&g[branch * 128 + 2 * lane]);
    float2 bv = *reinterpret_cast<const float2*>(&b[branch * 128 + 2 * lane]);
    bf16* orow = xn + (size_t)grow * 128;
    orow[2 * lane] = f2b((a.x - mean) * rstd * gv.x + bv.x);
    orow[2 * lane + 1] = f2b((a.y - mean) * rstd * gv.y + bv.y);
}

// ================= K2: QKV GEMM [4096x384x128] per branch, scatter to q/k/v =================
__global__ __launch_bounds__(384) void k_qkv(const bf16* __restrict__ xn, const float* __restrict__ w,
                                             bf16* __restrict__ q, bf16* __restrict__ k, bf16* __restrict__ v) {
    __shared__ float xl[32][128];
    int branch = blockIdx.x, rb = blockIdx.y;
    int tid = threadIdx.x;
    const bf16* xbase = xn + ((size_t)branch * 4096 + rb * 32) * 128;
    for (int i = tid; i < 32 * 128; i += 384) xl[i >> 7][i & 127] = b2f(xbase[i]);
    __syncthreads();
    int c = tid;  // 0..383
    const float* wc = w + (size_t)branch * 128 * 384 + c;
    float acc[32];
#pragma unroll
    for (int r = 0; r < 32; ++r) acc[r] = 0.f;
    for (int k0 = 0; k0 < 128; k0 += 4) {
        float w0 = wc[(k0 + 0) * 384];
        float w1 = wc[(k0 + 1) * 384];
        float w2 = wc[(k0 + 2) * 384];
        float w3 = wc[(k0 + 3) * 384];
#pragma unroll
        for (int r = 0; r < 32; ++r) {
            float4 xv = *reinterpret_cast<const float4*>(&xl[r][k0]);
            acc[r] += xv.x * w0 + xv.y * w1 + xv.z * w2 + xv.w * w3;
        }
    }
    int which = c >> 7, h = (c & 127) >> 4, d = c & 15;
    bf16* dst = (which == 0) ? q : (which == 1 ? k : v);
    int rowbase = rb * 32;
    for (int r = 0; r < 32; ++r) {
        int row = rowbase + r;              // row within branch = b*2048 + n
        int bb = row >> 11, n = row & 2047;
        size_t idx = ((((size_t)branch * 2 + bb) * 8 + h) * 2048 + n) * 16 + d;
        dst[idx] = f2b(acc[r]);
    }
}

// ================= K3: MFMA attention (swapped-operand flash) =================
// grid (48 bh, 16 qblocks); 256 threads = 4 waves; wave owns 32 q-rows.
// S^T = K(32x16) . Q^T(16x32) via mfma_32x32x16_bf16 -> lane holds 16 scores of q-row (lane&31).
// Online softmax in-register; P->bf16 via v_cvt_pk; lane-half exchange via shfl_xor(.,32).
// O^T += V^T(16x16 valid) . P^T via 2 mfma per 32-key chunk; V^T staged swizzled in 2KB LDS.
__global__ __launch_bounds__(256) void k_attn(const bf16* __restrict__ qg, const bf16* __restrict__ kg,
                                              const bf16* __restrict__ vg, bf16* __restrict__ o) {
    __shared__ short vt[16 * 64];   // V^T chunk [d=16][key=64], XOR-swizzled
    int bh = blockIdx.x;            // (branch*2+b)*8+h
    int qblk = blockIdx.y;          // 0..15
    size_t base = (size_t)bh * (2048 * 16);
    int tid = threadIdx.x, wave = tid >> 6, lane = tid & 63;
    int hi = lane >> 5, l31 = lane & 31;
    int qrow = qblk * 128 + wave * 32 + l31;   // q row within bh
    const short* qs = (const short*)qg;
    const short* ks = (const short*)kg;
    const short* vs = (const short*)vg;
    short8 qf = *(const short8*)&qs[base + (size_t)qrow * 16 + hi * 8];

    f32x16 acc;
#pragma unroll
    for (int r = 0; r < 16; ++r) acc[r] = 0.f;
    float m = -INFINITY, sum = 0.f;

    int skey = tid >> 2, sdg = (tid & 3) * 4;   // staging assignment

    for (int c0 = 0; c0 < 2048; c0 += 64) {
        __syncthreads();
        // stage V chunk transposed + swizzled
        short4v vv = *(const short4v*)&vs[base + (size_t)(c0 + skey) * 16 + sdg];
#pragma unroll
        for (int j = 0; j < 4; ++j) {
            int d = sdg + j;
            vt[(d * 64 + skey) ^ ((d & 7) << 3)] = vv[j];
        }
        __syncthreads();
#pragma unroll
        for (int sub = 0; sub < 2; ++sub) {
            int krow = c0 + sub * 32 + l31;
            short8 kf = *(const short8*)&ks[base + (size_t)krow * 16 + hi * 8];
            f32x16 zero;
#pragma unroll
            for (int r = 0; r < 16; ++r) zero[r] = 0.f;
            // S^T tile: reg r -> key (r&3)+8*(r>>2)+4*hi (within 32-chunk), col = q-row (lane&31)
            f32x16 s2 = __builtin_amdgcn_mfma_f32_32x32x16_bf16(kf, qf, zero, 0, 0, 0);
            float p[16];
            float cmax = -INFINITY;
#pragma unroll
            for (int r = 0; r < 16; ++r) { p[r] = s2[r] * 0.25f; cmax = fmaxf(cmax, p[r]); }
            cmax = fmaxf(cmax, __shfl_xor(cmax, 32));
            float mnew = fmaxf(m, cmax);
            float fac = __expf(m - mnew);
            float psum = 0.f;
#pragma unroll
            for (int r = 0; r < 16; ++r) { p[r] = __expf(p[r] - mnew); psum += p[r]; }
            psum += __shfl_xor(psum, 32);
            sum = sum * fac + psum;
            m = mnew;
#pragma unroll
            for (int r = 0; r < 16; ++r) acc[r] *= fac;
            // P -> bf16 pairs; w[e]=pack(p[2e],p[2e+1]); x[e]= partner half's w[e]
            unsigned w[8], x[8];
#pragma unroll
            for (int e = 0; e < 8; ++e) {
                unsigned t;
                asm("v_cvt_pk_bf16_f32 %0, %1, %2" : "=v"(t) : "v"(p[2 * e]), "v"(p[2 * e + 1]));
                w[e] = t;
                x[e] = (unsigned)__shfl_xor((int)t, 32);
            }
            // B-frag (P^T): lo lanes supply keys 0..7 / hi keys 8..15 of each 16-key group
            union { unsigned u[4]; short8 v; } b1, b2;
            b1.u[0] = hi ? x[2] : w[0];
            b1.u[1] = hi ? x[3] : w[1];
            b1.u[2] = hi ? w[2] : x[0];
            b1.u[3] = hi ? w[3] : x[1];
            b2.u[0] = hi ? x[6] : w[4];
            b2.u[1] = hi ? x[7] : w[5];
            b2.u[2] = hi ? w[6] : x[4];
            b2.u[3] = hi ? w[7] : x[5];
            // A-frag (V^T): row d = lane&15 (lanes 16..31 duplicate -> garbage rows ignored)
            int d = lane & 15;
            int i1 = (d * 64 + sub * 32 + hi * 8) ^ ((d & 7) << 3);
            int i2 = (d * 64 + sub * 32 + 16 + hi * 8) ^ ((d & 7) << 3);
            short8 vf1 = *(const short8*)&vt[i1];
            short8 vf2 = *(const short8*)&vt[i2];
            acc = __builtin_amdgcn_mfma_f32_32x32x16_bf16(vf1, b1.v, acc, 0, 0, 0);
            acc = __builtin_amdgcn_mfma_f32_32x32x16_bf16(vf2, b2.v, acc, 0, 0, 0);
        }
    }
    // epilogue: regs 0..7 hold O^T rows d=(r&3)+8*(r>>2)+4*hi for col q-row
    float inv = 1.f / sum;
    int branch = bh >> 4, bb = (bh >> 3) & 1, h = bh & 7;
    size_t orow = (size_t)branch * 4096 + (size_t)bb * 2048 + qrow;
    unsigned u0 = (unsigned)f2bu(acc[0] * inv) | ((unsigned)f2bu(acc[1] * inv) << 16);
    unsigned u1 = (unsigned)f2bu(acc[2] * inv) | ((unsigned)f2bu(acc[3] * inv) << 16);
    unsigned u2 = (unsigned)f2bu(acc[4] * inv) | ((unsigned)f2bu(acc[5] * inv) << 16);
    unsigned u3 = (unsigned)f2bu(acc[6] * inv) | ((unsigned)f2bu(acc[7] * inv) << 16);
    short* op = (short*)o;
    int2v w01; w01.x = (int)u0; w01.y = (int)u1;
    int2v w23; w23.x = (int)u2; w23.y = (int)u3;
    *(int2v*)&op[orow * 128 + h * 16 + 4 * hi] = w01;       // d = 4*hi .. 4*hi+3
    *(int2v*)&op[orow * 128 + h * 16 + 8 + 4 * hi] = w23;   // d = 8+4*hi .. 11+4*hi
}

// ================= K4: proj GEMM [4096x128x128] + bias + residual -> xc[4096][384] fp32 =================
__global__ __launch_bounds__(128) void k_proj(const bf16* __restrict__ o, const float* __restrict__ w,
                                              const float* __restrict__ pb, const float* __restrict__ x1,
                                              const float* __restrict__ x2, const float* __restrict__ x3,
                                              float* __restrict__ xc) {
    __shared__ float ol[32][128];
    int branch = blockIdx.x, rb = blockIdx.y, tid = threadIdx.x;
    const bf16* obase = o + ((size_t)branch * 4096 + rb * 32) * 128;
    for (int i = tid; i < 32 * 128; i += 128) ol[i >> 7][i & 127] = b2f(obase[i]);
    __syncthreads();
    int c = tid;
    const float* wc = w + (size_t)branch * 128 * 128 + c;
    float acc[32];
#pragma unroll
    for (int r = 0; r < 32; ++r) acc[r] = 0.f;
    for (int k0 = 0; k0 < 128; k0 += 4) {
        float w0 = wc[(k0 + 0) * 128];
        float w1 = wc[(k0 + 1) * 128];
        float w2 = wc[(k0 + 2) * 128];
        float w3 = wc[(k0 + 3) * 128];
#pragma unroll
        for (int r = 0; r < 32; ++r) {
            float4 xv = *reinterpret_cast<const float4*>(&ol[r][k0]);
            acc[r] += xv.x * w0 + xv.y * w1 + xv.z * w2 + xv.w * w3;
        }
    }
    float bias = pb[branch * 128 + c];
    const float* xp = (branch == 0) ? x1 : (branch == 1 ? x2 : x3);
    for (int r = 0; r < 32; ++r) {
        int row = rb * 32 + r;
        float res = xp[(size_t)row * 128 + c];
        xc[(size_t)row * 384 + branch * 128 + c] = acc[r] + bias + res;
    }
}

// ================= K5: LN2 over 384 features =================
__global__ __launch_bounds__(256) void k_ln2(const float* __restrict__ xc, const float* __restrict__ g,
                                             const float* __restrict__ b, bf16* __restrict__ xcn) {
    int tid = threadIdx.x, wave = tid >> 6, lane = tid & 63;
    int row = blockIdx.x * 4 + wave;  // 0..4095
    const float* rp = xc + (size_t)row * 384;
    float v[6];
    float s = 0.f, sq = 0.f;
#pragma unroll
    for (int i = 0; i < 6; ++i) {
        v[i] = rp[lane + i * 64];
        s += v[i]; sq += v[i] * v[i];
    }
#pragma unroll
    for (int off = 32; off >= 1; off >>= 1) { s += __shfl_xor(s, off); sq += __shfl_xor(sq, off); }
    float mean = s * (1.f / 384.f);
    float var = sq * (1.f / 384.f) - mean * mean;
    float rstd = rsqrtf(var + 1e-5f);
    bf16* op = xcn + (size_t)row * 384;
#pragma unroll
    for (int i = 0; i < 6; ++i) {
        int c = lane + i * 64;
        op[c] = f2b((v[i] - mean) * rstd * g[c] + b[c]);
    }
}

// ================= K6: FC1 [4096x768x384] + bias + exact GELU =================
__global__ __launch_bounds__(256) void k_fc1(const bf16* __restrict__ xcn, const float* __restrict__ w,
                                             const float* __restrict__ bias, bf16* __restrict__ h) {
    __shared__ float xl[32][384];  // 48 KB
    int rb = blockIdx.x, cb = blockIdx.y, tid = threadIdx.x;
    const bf16* xbase = xcn + (size_t)rb * 32 * 384;
    for (int i = tid; i < 32 * 384; i += 256) {
        int r = i / 384, kk = i - r * 384;
        xl[r][kk] = b2f(xbase[i]);
    }
    __syncthreads();
    int c = cb * 256 + tid;  // 0..767
    const float* wc = w + c;
    float acc[32];
#pragma unroll
    for (int r = 0; r < 32; ++r) acc[r] = 0.f;
    for (int k0 = 0; k0 < 384; k0 += 4) {
        float w0 = wc[(size_t)(k0 + 0) * 768];
        float w1 = wc[(size_t)(k0 + 1) * 768];
        float w2 = wc[(size_t)(k0 + 2) * 768];
        float w3 = wc[(size_t)(k0 + 3) * 768];
#pragma unroll
        for (int r = 0; r < 32; ++r) {
            float4 xv = *reinterpret_cast<const float4*>(&xl[r][k0]);
            acc[r] += xv.x * w0 + xv.y * w1 + xv.z * w2 + xv.w * w3;
        }
    }
    float bs = bias[c];
    for (int r = 0; r < 32; ++r) {
        float vv = acc[r] + bs;
        float ge = 0.5f * vv * (1.f + erff(vv * 0.70710678118f));
        h[((size_t)rb * 32 + r) * 768 + c] = f2b(ge);
    }
}

// ================= K7: FC2 [4096x384x768] + bias + residual -> split fp32 outputs =================
__global__ __launch_bounds__(384) void k_fc2(const bf16* __restrict__ h, const float* __restrict__ w,
                                             const float* __restrict__ bias, const float* __restrict__ xc,
                                             float* __restrict__ outp) {
    __shared__ float hl[32][384];  // 48 KB, two K-passes of 384
    int rb = blockIdx.x, tid = threadIdx.x;
    int c = tid;  // 0..383
    float acc[32];
#pragma unroll
    for (int r = 0; r < 32; ++r) acc[r] = 0.f;
    for (int p = 0; p < 2; ++p) {
        __syncthreads();
        const bf16* hbase = h + (size_t)rb * 32 * 768 + p * 384;
        for (int t = 0; t < 32; ++t) hl[t][tid] = b2f(hbase[(size_t)t * 768 + tid]);
        __syncthreads();
        const float* wc = w + (size_t)p * 384 * 384 + c;
        for (int k0 = 0; k0 < 384; k0 += 4) {
            float w0 = wc[(size_t)(k0 + 0) * 384];
            float w1 = wc[(size_t)(k0 + 1) * 384];
            float w2 = wc[(size_t)(k0 + 2) * 384];
            float w3 = wc[(size_t)(k0 + 3) * 384];
#pragma unroll
            for (int r = 0; r < 32; ++r) {
                float4 hv = *reinterpret_cast<const float4*>(&hl[r][k0]);
                acc[r] += hv.x * w0 + hv.y * w1 + hv.z * w2 + hv.w * w3;
            }
        }
    }
    float bs = bias[c];
    int which = c >> 7, cc = c & 127;
    for (int r = 0; r < 32; ++r) {
        size_t row = (size_t)rb * 32 + r;
        float res = xc[row * 384 + c];
        outp[(size_t)which * 524288 + row * 128 + cc] = acc[r] + bs + res;
    }
}

// ================= launch =================
extern "C" void kernel_launch(void* const* d_in, const int* in_sizes, int n_in,
                              void* d_out, int out_size, void* d_ws, size_t ws_size,
                              hipStream_t stream) {
    const float* x1     = (const float*)d_in[0];
    const float* x2     = (const float*)d_in[1];
    const float* x3     = (const float*)d_in[2];
    const float* ln1_g  = (const float*)d_in[3];
    const float* ln1_b  = (const float*)d_in[4];
    const float* qkv_w  = (const float*)d_in[5];
    const float* proj_w = (const float*)d_in[6];
    const float* proj_b = (const float*)d_in[7];
    const float* ln2_g  = (const float*)d_in[8];
    const float* ln2_b  = (const float*)d_in[9];
    const float* fc1_w  = (const float*)d_in[10];
    const float* fc1_b  = (const float*)d_in[11];
    const float* fc2_w  = (const float*)d_in[12];
    const float* fc2_b  = (const float*)d_in[13];

    char* ws = (char*)d_ws;
    const size_t SB = 3145728;  // 3*4096*128*2 bytes (bf16 buffer of 1.5M elems)
    bf16* xn  = (bf16*)(ws + 0 * SB);
    bf16* qb  = (bf16*)(ws + 1 * SB);
    bf16* kb  = (bf16*)(ws + 2 * SB);
    bf16* vb  = (bf16*)(ws + 3 * SB);
    bf16* ob  = (bf16*)(ws + 4 * SB);
    float* xc = (float*)(ws + 5 * SB);            // 4096*384*4 = 6291456 B
    bf16* xcn = (bf16*)(ws + 5 * SB + 6291456);   // 3145728 B
    bf16* hb  = (bf16*)(ws + 6 * SB + 6291456);   // 4096*768*2 = 6291456 B
    // total = 31457280 B (30 MB)

    k_ln1<<<3072, 256, 0, stream>>>(x1, x2, x3, ln1_g, ln1_b, xn);
    k_qkv<<<dim3(3, 128), 384, 0, stream>>>(xn, qkv_w, qb, kb, vb);
    k_attn<<<dim3(48, 16), 256, 0, stream>>>(qb, kb, vb, ob);
    k_proj<<<dim3(3, 128), 128, 0, stream>>>(ob, proj_w, proj_b, x1, x2, x3, xc);
    k_ln2<<<1024, 256, 0, stream>>>(xc, ln2_g, ln2_b, xcn);
    k_fc1<<<dim3(128, 3), 256, 0, stream>>>(xcn, fc1_w, fc1_b, hb);
    k_fc2<<<128, 384, 0, stream>>>(hb, fc2_w, fc2_b, xc, (float*)d_out);
}

// Round 5
// 139.103 us; speedup vs baseline: 7.4537x; 3.0553x over previous
//
#include <hip/hip_runtime.h>
#include <hip/hip_bf16.h>

typedef __hip_bfloat16 bf16;

// ---------- constants ----------
// B=2, N=2048, C=128, H=8, hd=16, branches=3, hid=768
// rows per branch = B*N = 4096; 3C = 384
// I/O fp32; intermediates bf16 except xc (fp32 residual). Weights pre-transposed
// to bf16 Wt[N][K] by k_wt so all GEMM operands are row x contiguous-K.

static __device__ __forceinline__ float b2f(bf16 h) { return __bfloat162float(h); }
static __device__ __forceinline__ bf16 f2b(float f) { return __float2bfloat16(f); }
static __device__ __forceinline__ unsigned short f2bu(float f) {
    bf16 h = f2b(f);
    return *reinterpret_cast<unsigned short*>(&h);
}

typedef __attribute__((ext_vector_type(8))) short short8;
typedef __attribute__((ext_vector_type(4))) short short4v;
typedef __attribute__((ext_vector_type(16))) float f32x16;
typedef __attribute__((ext_vector_type(2))) int int2v;

// ================= K0: weight transpose+convert  src[b][Kd][Nd] f32 -> dst[b][Nd][Kd] bf16 =================
__global__ __launch_bounds__(256) void k_wt(const float* __restrict__ src, bf16* __restrict__ dst,
                                            int Kd, int Nd) {
    int b = blockIdx.y;
    size_t total = (size_t)Kd * Nd;
    size_t idx = (size_t)blockIdx.x * 256 + threadIdx.x;
    if (idx >= total) return;
    int n = (int)(idx / Kd), k = (int)(idx - (size_t)n * Kd);
    dst[(size_t)b * total + idx] = f2b(src[(size_t)b * total + (size_t)k * Nd + n]);
}

// ================= shared MFMA GEMM tile: C64x64 = A[M,K] . Wt[N,K]^T =================
// 256 threads = 4 waves (2x2 of 32x32). LDS tiles [64][64] bf16, XOR block-swizzle kb^=(r&7).
__device__ __forceinline__ f32x16 gemm_tile(const short* __restrict__ A, const short* __restrict__ W,
                                            int K, int rowbase, int colbase,
                                            short* als, short* wls) {
    int tid = threadIdx.x;
    int wid = tid >> 6, lane = tid & 63;
    int hi = lane >> 5, l31 = lane & 31;
    int wm = wid >> 1, wn = wid & 1;
    int sr = tid >> 3, skb = tid & 7;   // staging: row (0..31), k-block (0..7)
    f32x16 acc;
#pragma unroll
    for (int i = 0; i < 16; ++i) acc[i] = 0.f;
    for (int k0 = 0; k0 < K; k0 += 64) {
        __syncthreads();
#pragma unroll
        for (int pass = 0; pass < 2; ++pass) {
            int r = sr + pass * 32;
            short8 av = *(const short8*)&A[(size_t)(rowbase + r) * K + k0 + skb * 8];
            *(short8*)&als[r * 64 + ((skb ^ (r & 7)) * 8)] = av;
            short8 wv = *(const short8*)&W[(size_t)(colbase + r) * K + k0 + skb * 8];
            *(short8*)&wls[r * 64 + ((skb ^ (r & 7)) * 8)] = wv;
        }
        __syncthreads();
#pragma unroll
        for (int ks = 0; ks < 4; ++ks) {
            int ra = wm * 32 + l31;
            int rb = wn * 32 + l31;
            int kb = ks * 2 + hi;
            short8 af = *(const short8*)&als[ra * 64 + ((kb ^ (ra & 7)) * 8)];
            short8 bf = *(const short8*)&wls[rb * 64 + ((kb ^ (rb & 7)) * 8)];
            acc = __builtin_amdgcn_mfma_f32_32x32x16_bf16(af, bf, acc, 0, 0, 0);
        }
    }
    return acc;
}

// ================= K1: LN1 for all 3 branches =================
__global__ __launch_bounds__(256) void k_ln1(const float* __restrict__ x1, const float* __restrict__ x2,
                                             const float* __restrict__ x3, const float* __restrict__ g,
                                             const float* __restrict__ b, bf16* __restrict__ xn) {
    int tid = threadIdx.x;
    int wave = tid >> 6, lane = tid & 63;
    int grow = blockIdx.x * 4 + wave;      // 0..12287
    int branch = grow >> 12;
    const float* xp = (branch == 0) ? x1 : (branch == 1 ? x2 : x3);
    const float* row = xp + (size_t)(grow & 4095) * 128;
    float2 a = *reinterpret_cast<const float2*>(&row[2 * lane]);
    float s = a.x + a.y, sq = a.x * a.x + a.y * a.y;
#pragma unroll
    for (int off = 32; off >= 1; off >>= 1) { s += __shfl_xor(s, off); sq += __shfl_xor(sq, off); }
    float mean = s * (1.f / 128.f);
    float var = sq * (1.f / 128.f) - mean * mean;
    float rstd = rsqrtf(var + 1e-5f);
    float2 gv = *reinterpret_cast<const float2*>(&g[branch * 128 + 2 * lane]);
    float2 bv = *reinterpret_cast<const float2*>(&b[branch * 128 + 2 * lane]);
    bf16* orow = xn + (size_t)grow * 128;
    orow[2 * lane] = f2b((a.x - mean) * rstd * gv.x + bv.x);
    orow[2 * lane + 1] = f2b((a.y - mean) * rstd * gv.y + bv.y);
}

// ================= K2: QKV GEMM (MFMA) + scatter to q/k/v head layout =================
__global__ __launch_bounds__(256) void k_qkv_m(const bf16* __restrict__ xn, const bf16* __restrict__ wt,
                                               bf16* __restrict__ q, bf16* __restrict__ k, bf16* __restrict__ v) {
    __shared__ short als[64 * 64];
    __shared__ short wls[64 * 64];
    int branch = blockIdx.z;
    const short* A = (const short*)xn + (size_t)branch * 4096 * 128;
    const short* W = (const short*)wt + (size_t)branch * 384 * 128;
    int rowbase = blockIdx.x * 64, colbase = blockIdx.y * 64;
    f32x16 acc = gemm_tile(A, W, 128, rowbase, colbase, als, wls);
    int tid = threadIdx.x, wid = tid >> 6, lane = tid & 63;
    int hi = lane >> 5, l31 = lane & 31;
    int wm = wid >> 1, wn = wid & 1;
    int c = colbase + wn * 32 + l31;        // 0..383
    int which = c >> 7, h = (c >> 4) & 7, d = c & 15;
    bf16* dst = (which == 0) ? q : (which == 1 ? k : v);
#pragma unroll
    for (int i = 0; i < 16; ++i) {
        int mrow = (i & 3) + 8 * (i >> 2) + 4 * hi;
        int token = rowbase + wm * 32 + mrow;
        int bb = token >> 11, n = token & 2047;
        dst[((((size_t)branch * 2 + bb) * 8 + h) * 2048 + n) * 16 + d] = f2b(acc[i]);
    }
}

// ================= K3: MFMA attention (swapped-operand flash) =================
__global__ __launch_bounds__(256) void k_attn(const bf16* __restrict__ qg, const bf16* __restrict__ kg,
                                              const bf16* __restrict__ vg, bf16* __restrict__ o) {
    __shared__ short vt[16 * 64];   // V^T chunk [d=16][key=64], XOR-swizzled
    int bh = blockIdx.x;            // (branch*2+b)*8+h
    int qblk = blockIdx.y;          // 0..15
    size_t base = (size_t)bh * (2048 * 16);
    int tid = threadIdx.x, wave = tid >> 6, lane = tid & 63;
    int hi = lane >> 5, l31 = lane & 31;
    int qrow = qblk * 128 + wave * 32 + l31;
    const short* qs = (const short*)qg;
    const short* ks = (const short*)kg;
    const short* vs = (const short*)vg;
    short8 qf = *(const short8*)&qs[base + (size_t)qrow * 16 + hi * 8];

    f32x16 acc;
#pragma unroll
    for (int r = 0; r < 16; ++r) acc[r] = 0.f;
    float m = -INFINITY, sum = 0.f;

    int skey = tid >> 2, sdg = (tid & 3) * 4;

    for (int c0 = 0; c0 < 2048; c0 += 64) {
        __syncthreads();
        short4v vv = *(const short4v*)&vs[base + (size_t)(c0 + skey) * 16 + sdg];
#pragma unroll
        for (int j = 0; j < 4; ++j) {
            int d = sdg + j;
            vt[(d * 64 + skey) ^ ((d & 7) << 3)] = vv[j];
        }
        __syncthreads();
#pragma unroll
        for (int sub = 0; sub < 2; ++sub) {
            int krow = c0 + sub * 32 + l31;
            short8 kf = *(const short8*)&ks[base + (size_t)krow * 16 + hi * 8];
            f32x16 zero;
#pragma unroll
            for (int r = 0; r < 16; ++r) zero[r] = 0.f;
            f32x16 s2 = __builtin_amdgcn_mfma_f32_32x32x16_bf16(kf, qf, zero, 0, 0, 0);
            float p[16];
            float cmax = -INFINITY;
#pragma unroll
            for (int r = 0; r < 16; ++r) { p[r] = s2[r] * 0.25f; cmax = fmaxf(cmax, p[r]); }
            cmax = fmaxf(cmax, __shfl_xor(cmax, 32));
            float mnew = fmaxf(m, cmax);
            float fac = __expf(m - mnew);
            float psum = 0.f;
#pragma unroll
            for (int r = 0; r < 16; ++r) { p[r] = __expf(p[r] - mnew); psum += p[r]; }
            psum += __shfl_xor(psum, 32);
            sum = sum * fac + psum;
            m = mnew;
#pragma unroll
            for (int r = 0; r < 16; ++r) acc[r] *= fac;
            unsigned w[8], x[8];
#pragma unroll
            for (int e = 0; e < 8; ++e) {
                unsigned t;
                asm("v_cvt_pk_bf16_f32 %0, %1, %2" : "=v"(t) : "v"(p[2 * e]), "v"(p[2 * e + 1]));
                w[e] = t;
                x[e] = (unsigned)__shfl_xor((int)t, 32);
            }
            union { unsigned u[4]; short8 v; } b1, b2;
            b1.u[0] = hi ? x[2] : w[0];
            b1.u[1] = hi ? x[3] : w[1];
            b1.u[2] = hi ? w[2] : x[0];
            b1.u[3] = hi ? w[3] : x[1];
            b2.u[0] = hi ? x[6] : w[4];
            b2.u[1] = hi ? x[7] : w[5];
            b2.u[2] = hi ? w[6] : x[4];
            b2.u[3] = hi ? w[7] : x[5];
            int d = lane & 15;
            int i1 = (d * 64 + sub * 32 + hi * 8) ^ ((d & 7) << 3);
            int i2 = (d * 64 + sub * 32 + 16 + hi * 8) ^ ((d & 7) << 3);
            short8 vf1 = *(const short8*)&vt[i1];
            short8 vf2 = *(const short8*)&vt[i2];
            acc = __builtin_amdgcn_mfma_f32_32x32x16_bf16(vf1, b1.v, acc, 0, 0, 0);
            acc = __builtin_amdgcn_mfma_f32_32x32x16_bf16(vf2, b2.v, acc, 0, 0, 0);
        }
    }
    float inv = 1.f / sum;
    int branch = bh >> 4, bb = (bh >> 3) & 1, h = bh & 7;
    size_t orow = (size_t)branch * 4096 + (size_t)bb * 2048 + qrow;
    unsigned u0 = (unsigned)f2bu(acc[0] * inv) | ((unsigned)f2bu(acc[1] * inv) << 16);
    unsigned u1 = (unsigned)f2bu(acc[2] * inv) | ((unsigned)f2bu(acc[3] * inv) << 16);
    unsigned u2 = (unsigned)f2bu(acc[4] * inv) | ((unsigned)f2bu(acc[5] * inv) << 16);
    unsigned u3 = (unsigned)f2bu(acc[6] * inv) | ((unsigned)f2bu(acc[7] * inv) << 16);
    short* op = (short*)o;
    int2v w01; w01.x = (int)u0; w01.y = (int)u1;
    int2v w23; w23.x = (int)u2; w23.y = (int)u3;
    *(int2v*)&op[orow * 128 + h * 16 + 4 * hi] = w01;
    *(int2v*)&op[orow * 128 + h * 16 + 8 + 4 * hi] = w23;
}

// ================= K4: proj GEMM (MFMA) + bias + residual -> xc[4096][384] fp32 =================
__global__ __launch_bounds__(256) void k_proj_m(const bf16* __restrict__ ob, const bf16* __restrict__ wt,
                                                const float* __restrict__ pb, const float* __restrict__ x1,
                                                const float* __restrict__ x2, const float* __restrict__ x3,
                                                float* __restrict__ xc) {
    __shared__ short als[64 * 64];
    __shared__ short wls[64 * 64];
    int branch = blockIdx.z;
    const short* A = (const short*)ob + (size_t)branch * 4096 * 128;
    const short* W = (const short*)wt + (size_t)branch * 128 * 128;
    int rowbase = blockIdx.x * 64, colbase = blockIdx.y * 64;
    f32x16 acc = gemm_tile(A, W, 128, rowbase, colbase, als, wls);
    int tid = threadIdx.x, wid = tid >> 6, lane = tid & 63;
    int hi = lane >> 5, l31 = lane & 31;
    int wm = wid >> 1, wn = wid & 1;
    int c = colbase + wn * 32 + l31;        // 0..127
    float bias = pb[branch * 128 + c];
    const float* xp = (branch == 0) ? x1 : (branch == 1 ? x2 : x3);
#pragma unroll
    for (int i = 0; i < 16; ++i) {
        int mrow = (i & 3) + 8 * (i >> 2) + 4 * hi;
        int row = rowbase + wm * 32 + mrow;
        xc[(size_t)row * 384 + branch * 128 + c] = acc[i] + bias + xp[(size_t)row * 128 + c];
    }
}

// ================= K5: LN2 over 384 features =================
__global__ __launch_bounds__(256) void k_ln2(const float* __restrict__ xc, const float* __restrict__ g,
                                             const float* __restrict__ b, bf16* __restrict__ xcn) {
    int tid = threadIdx.x, wave = tid >> 6, lane = tid & 63;
    int row = blockIdx.x * 4 + wave;  // 0..4095
    const float* rp = xc + (size_t)row * 384;
    float v[6];
    float s = 0.f, sq = 0.f;
#pragma unroll
    for (int i = 0; i < 6; ++i) {
        v[i] = rp[lane + i * 64];
        s += v[i]; sq += v[i] * v[i];
    }
#pragma unroll
    for (int off = 32; off >= 1; off >>= 1) { s += __shfl_xor(s, off); sq += __shfl_xor(sq, off); }
    float mean = s * (1.f / 384.f);
    float var = sq * (1.f / 384.f) - mean * mean;
    float rstd = rsqrtf(var + 1e-5f);
    bf16* op = xcn + (size_t)row * 384;
#pragma unroll
    for (int i = 0; i < 6; ++i) {
        int c = lane + i * 64;
        op[c] = f2b((v[i] - mean) * rstd * g[c] + b[c]);
    }
}

// ================= K6: FC1 GEMM (MFMA) + bias + exact GELU -> h bf16 =================
__global__ __launch_bounds__(256) void k_fc1_m(const bf16* __restrict__ xcn, const bf16* __restrict__ wt,
                                               const float* __restrict__ bias, bf16* __restrict__ h) {
    __shared__ short als[64 * 64];
    __shared__ short wls[64 * 64];
    const short* A = (const short*)xcn;
    const short* W = (const short*)wt;
    int rowbase = blockIdx.x * 64, colbase = blockIdx.y * 64;
    f32x16 acc = gemm_tile(A, W, 384, rowbase, colbase, als, wls);
    int tid = threadIdx.x, wid = tid >> 6, lane = tid & 63;
    int hi = lane >> 5, l31 = lane & 31;
    int wm = wid >> 1, wn = wid & 1;
    int c = colbase + wn * 32 + l31;        // 0..767
    float bs = bias[c];
#pragma unroll
    for (int i = 0; i < 16; ++i) {
        int mrow = (i & 3) + 8 * (i >> 2) + 4 * hi;
        int row = rowbase + wm * 32 + mrow;
        float vv = acc[i] + bs;
        float ge = 0.5f * vv * (1.f + erff(vv * 0.70710678118f));
        h[(size_t)row * 768 + c] = f2b(ge);
    }
}

// ================= K7: FC2 GEMM (MFMA) + bias + residual -> split fp32 outputs =================
__global__ __launch_bounds__(256) void k_fc2_m(const bf16* __restrict__ h, const bf16* __restrict__ wt,
                                               const float* __restrict__ bias, const float* __restrict__ xc,
                                               float* __restrict__ outp) {
    __shared__ short als[64 * 64];
    __shared__ short wls[64 * 64];
    const short* A = (const short*)h;
    const short* W = (const short*)wt;
    int rowbase = blockIdx.x * 64, colbase = blockIdx.y * 64;
    f32x16 acc = gemm_tile(A, W, 768, rowbase, colbase, als, wls);
    int tid = threadIdx.x, wid = tid >> 6, lane = tid & 63;
    int hi = lane >> 5, l31 = lane & 31;
    int wm = wid >> 1, wn = wid & 1;
    int c = colbase + wn * 32 + l31;        // 0..383
    float bs = bias[c];
    int which = c >> 7, cc = c & 127;
#pragma unroll
    for (int i = 0; i < 16; ++i) {
        int mrow = (i & 3) + 8 * (i >> 2) + 4 * hi;
        int row = rowbase + wm * 32 + mrow;
        outp[(size_t)which * 524288 + (size_t)row * 128 + cc] = acc[i] + bs + xc[(size_t)row * 384 + c];
    }
}

// ================= launch =================
extern "C" void kernel_launch(void* const* d_in, const int* in_sizes, int n_in,
                              void* d_out, int out_size, void* d_ws, size_t ws_size,
                              hipStream_t stream) {
    const float* x1     = (const float*)d_in[0];
    const float* x2     = (const float*)d_in[1];
    const float* x3     = (const float*)d_in[2];
    const float* ln1_g  = (const float*)d_in[3];
    const float* ln1_b  = (const float*)d_in[4];
    const float* qkv_w  = (const float*)d_in[5];
    const float* proj_w = (const float*)d_in[6];
    const float* proj_b = (const float*)d_in[7];
    const float* ln2_g  = (const float*)d_in[8];
    const float* ln2_b  = (const float*)d_in[9];
    const float* fc1_w  = (const float*)d_in[10];
    const float* fc1_b  = (const float*)d_in[11];
    const float* fc2_w  = (const float*)d_in[12];
    const float* fc2_b  = (const float*)d_in[13];

    char* ws = (char*)d_ws;
    const size_t SB = 3145728;  // bf16 buffer of 1.5M elems
    bf16* xn  = (bf16*)(ws + 0 * SB);
    bf16* qb  = (bf16*)(ws + 1 * SB);
    bf16* kb  = (bf16*)(ws + 2 * SB);
    bf16* vb  = (bf16*)(ws + 3 * SB);
    bf16* ob  = (bf16*)(ws + 4 * SB);
    float* xc = (float*)(ws + 5 * SB);            // 4096*384*4 = 6291456 B
    bf16* xcn = (bf16*)(ws + 5 * SB + 6291456);   // 3145728 B
    bf16* hb  = (bf16*)(ws + 6 * SB + 6291456);   // 4096*768*2 = 6291456 B
    char* wbase = ws + 31457280;
    bf16* wtq = (bf16*)(wbase);                   // 3*384*128*2 = 294912
    bf16* wtp = (bf16*)(wbase + 294912);          // 3*128*128*2 = 98304
    bf16* wt1 = (bf16*)(wbase + 393216);          // 768*384*2   = 589824
    bf16* wt2 = (bf16*)(wbase + 983040);          // 384*768*2   = 589824
    // total = 33030144 B (~31.5 MB)

    k_wt<<<dim3((128 * 384 + 255) / 256, 3), 256, 0, stream>>>(qkv_w, wtq, 128, 384);
    k_wt<<<dim3((128 * 128 + 255) / 256, 3), 256, 0, stream>>>(proj_w, wtp, 128, 128);
    k_wt<<<dim3((384 * 768 + 255) / 256, 1), 256, 0, stream>>>(fc1_w, wt1, 384, 768);
    k_wt<<<dim3((768 * 384 + 255) / 256, 1), 256, 0, stream>>>(fc2_w, wt2, 768, 384);

    k_ln1<<<3072, 256, 0, stream>>>(x1, x2, x3, ln1_g, ln1_b, xn);
    k_qkv_m<<<dim3(64, 6, 3), 256, 0, stream>>>(xn, wtq, qb, kb, vb);
    k_attn<<<dim3(48, 16), 256, 0, stream>>>(qb, kb, vb, ob);
    k_proj_m<<<dim3(64, 2, 3), 256, 0, stream>>>(ob, wtp, proj_b, x1, x2, x3, xc);
    k_ln2<<<1024, 256, 0, stream>>>(xc, ln2_g, ln2_b, xcn);
    k_fc1_m<<<dim3(64, 12, 1), 256, 0, stream>>>(xcn, wt1, fc1_b, hb);
    k_fc2_m<<<dim3(64, 6, 1), 256, 0, stream>>>(hb, wt2, fc2_b, xc, (float*)d_out);
}

// Round 6
// 112.002 us; speedup vs baseline: 9.2572x; 1.2420x over previous
//
#include <hip/hip_runtime.h>
#include <hip/hip_bf16.h>

typedef __hip_bfloat16 bf16;

// ---------- constants ----------
// B=2, N=2048, C=128, H=8, hd=16, branches=3, hid=768
// rows per branch = B*N = 4096; 3C = 384
// I/O fp32; intermediates bf16 except xc (fp32 residual). Weights pre-transposed
// to bf16 Wt[N][K] by k_wt_all. Q is pre-scaled by 0.25*log2e so attention
// softmax runs in the exp2 domain with no per-score scaling.

static __device__ __forceinline__ float b2f(bf16 h) { return __bfloat162float(h); }
static __device__ __forceinline__ bf16 f2b(float f) { return __float2bfloat16(f); }
static __device__ __forceinline__ unsigned short f2bu(float f) {
    bf16 h = f2b(f);
    return *reinterpret_cast<unsigned short*>(&h);
}

typedef __attribute__((ext_vector_type(8))) short short8;
typedef __attribute__((ext_vector_type(4))) short short4v;
typedef __attribute__((ext_vector_type(16))) float f32x16;
typedef __attribute__((ext_vector_type(2))) int int2v;

#define QSCALE 0.36067376022224085f  // 0.25 * log2(e)

// partner-half exchange via permlane32_swap (VALU, replaces ds_bpermute shfl_xor(.,32))
static __device__ __forceinline__ float xhalf(float x, int hi) {
    auto r = __builtin_amdgcn_permlane32_swap(__float_as_int(x), __float_as_int(x), false, false);
    return __int_as_float(hi ? r[0] : r[1]);
}

// ================= K0: all weight transposes+convert in one launch =================
// wtq[b][n<384][k<128] <- qkv_w[b][k][n]; wtp[b][n<128][k<128] <- proj_w[b][k][n]
// wt1[n<768][k<384] <- fc1_w[k][n];       wt2[n<384][k<768] <- fc2_w[k][n]
__global__ __launch_bounds__(256) void k_wt_all(const float* __restrict__ qkv_w, const float* __restrict__ proj_w,
                                                const float* __restrict__ fc1_w, const float* __restrict__ fc2_w,
                                                bf16* __restrict__ wtq, bf16* __restrict__ wtp,
                                                bf16* __restrict__ wt1, bf16* __restrict__ wt2) {
    int idx = blockIdx.x * 256 + threadIdx.x;   // < 786432
    if (idx < 147456) {
        int b = idx / 49152, i2 = idx % 49152;
        int n = i2 >> 7, k = i2 & 127;
        wtq[idx] = f2b(qkv_w[b * 49152 + k * 384 + n]);
    } else if (idx < 196608) {
        int j = idx - 147456;
        int b = j / 16384, i2 = j % 16384;
        int n = i2 >> 7, k = i2 & 127;
        wtp[j] = f2b(proj_w[b * 16384 + k * 128 + n]);
    } else if (idx < 491520) {
        int j = idx - 196608;
        int n = j / 384, k = j - n * 384;
        wt1[j] = f2b(fc1_w[k * 768 + n]);
    } else {
        int j = idx - 491520;
        int n = j / 768, k = j - n * 768;
        wt2[j] = f2b(fc2_w[k * 384 + n]);
    }
}

// ================= shared MFMA GEMM tile: C64x64 = A[M,K] . Wt[N,K]^T =================
// 256 threads = 4 waves (2x2 of 32x32). LDS tiles [64][64] bf16, XOR block-swizzle kb^=(r&7).
__device__ __forceinline__ f32x16 gemm_tile(const short* __restrict__ A, const short* __restrict__ W,
                                            int K, int rowbase, int colbase,
                                            short* als, short* wls) {
    int tid = threadIdx.x;
    int wid = tid >> 6, lane = tid & 63;
    int hi = lane >> 5, l31 = lane & 31;
    int wm = wid >> 1, wn = wid & 1;
    int sr = tid >> 3, skb = tid & 7;   // staging: row (0..31), k-block (0..7)
    f32x16 acc;
#pragma unroll
    for (int i = 0; i < 16; ++i) acc[i] = 0.f;
    for (int k0 = 0; k0 < K; k0 += 64) {
        __syncthreads();
#pragma unroll
        for (int pass = 0; pass < 2; ++pass) {
            int r = sr + pass * 32;
            short8 av = *(const short8*)&A[(size_t)(rowbase + r) * K + k0 + skb * 8];
            *(short8*)&als[r * 64 + ((skb ^ (r & 7)) * 8)] = av;
            short8 wv = *(const short8*)&W[(size_t)(colbase + r) * K + k0 + skb * 8];
            *(short8*)&wls[r * 64 + ((skb ^ (r & 7)) * 8)] = wv;
        }
        __syncthreads();
#pragma unroll
        for (int ks = 0; ks < 4; ++ks) {
            int ra = wm * 32 + l31;
            int rb = wn * 32 + l31;
            int kb = ks * 2 + hi;
            short8 af = *(const short8*)&als[ra * 64 + ((kb ^ (ra & 7)) * 8)];
            short8 bf = *(const short8*)&wls[rb * 64 + ((kb ^ (rb & 7)) * 8)];
            acc = __builtin_amdgcn_mfma_f32_32x32x16_bf16(af, bf, acc, 0, 0, 0);
        }
    }
    return acc;
}

// ================= K1: LN1 for all 3 branches =================
__global__ __launch_bounds__(256) void k_ln1(const float* __restrict__ x1, const float* __restrict__ x2,
                                             const float* __restrict__ x3, const float* __restrict__ g,
                                             const float* __restrict__ b, bf16* __restrict__ xn) {
    int tid = threadIdx.x;
    int wave = tid >> 6, lane = tid & 63;
    int grow = blockIdx.x * 4 + wave;      // 0..12287
    int branch = grow >> 12;
    const float* xp = (branch == 0) ? x1 : (branch == 1 ? x2 : x3);
    const float* row = xp + (size_t)(grow & 4095) * 128;
    float2 a = *reinterpret_cast<const float2*>(&row[2 * lane]);
    float s = a.x + a.y, sq = a.x * a.x + a.y * a.y;
#pragma unroll
    for (int off = 32; off >= 1; off >>= 1) { s += __shfl_xor(s, off); sq += __shfl_xor(sq, off); }
    float mean = s * (1.f / 128.f);
    float var = sq * (1.f / 128.f) - mean * mean;
    float rstd = rsqrtf(var + 1e-5f);
    float2 gv = *reinterpret_cast<const float2*>(&g[branch * 128 + 2 * lane]);
    float2 bv = *reinterpret_cast<const float2*>(&b[branch * 128 + 2 * lane]);
    bf16* orow = xn + (size_t)grow * 128;
    orow[2 * lane] = f2b((a.x - mean) * rstd * gv.x + bv.x);
    orow[2 * lane + 1] = f2b((a.y - mean) * rstd * gv.y + bv.y);
}

// ================= K2: QKV GEMM (MFMA) + scatter to q/k/v head layout (Q pre-scaled) =================
__global__ __launch_bounds__(256) void k_qkv_m(const bf16* __restrict__ xn, const bf16* __restrict__ wt,
                                               bf16* __restrict__ q, bf16* __restrict__ k, bf16* __restrict__ v) {
    __shared__ short als[64 * 64];
    __shared__ short wls[64 * 64];
    int branch = blockIdx.z;
    const short* A = (const short*)xn + (size_t)branch * 4096 * 128;
    const short* W = (const short*)wt + (size_t)branch * 384 * 128;
    int rowbase = blockIdx.x * 64, colbase = blockIdx.y * 64;
    f32x16 acc = gemm_tile(A, W, 128, rowbase, colbase, als, wls);
    int tid = threadIdx.x, wid = tid >> 6, lane = tid & 63;
    int hi = lane >> 5, l31 = lane & 31;
    int wm = wid >> 1, wn = wid & 1;
    int c = colbase + wn * 32 + l31;        // 0..383
    int which = c >> 7, h = (c >> 4) & 7, d = c & 15;
    bf16* dst = (which == 0) ? q : (which == 1 ? k : v);
    float scl = (which == 0) ? QSCALE : 1.0f;
#pragma unroll
    for (int i = 0; i < 16; ++i) {
        int mrow = (i & 3) + 8 * (i >> 2) + 4 * hi;
        int token = rowbase + wm * 32 + mrow;
        int bb = token >> 11, n = token & 2047;
        dst[((((size_t)branch * 2 + bb) * 8 + h) * 2048 + n) * 16 + d] = f2b(acc[i] * scl);
    }
}

// ================= K3: MFMA attention (swapped-operand flash, exp2-domain, defer-max, permlane) =================
__global__ __launch_bounds__(256) void k_attn(const bf16* __restrict__ qg, const bf16* __restrict__ kg,
                                              const bf16* __restrict__ vg, bf16* __restrict__ o) {
    __shared__ short vt[16 * 64];   // V^T chunk [d=16][key=64], XOR-swizzled
    int bh = blockIdx.x;            // (branch*2+b)*8+h
    int qblk = blockIdx.y;          // 0..15
    size_t base = (size_t)bh * (2048 * 16);
    int tid = threadIdx.x, wave = tid >> 6, lane = tid & 63;
    int hi = lane >> 5, l31 = lane & 31;
    int qrow = qblk * 128 + wave * 32 + l31;
    const short* qs = (const short*)qg;
    const short* ks = (const short*)kg;
    const short* vs = (const short*)vg;
    short8 qf = *(const short8*)&qs[base + (size_t)qrow * 16 + hi * 8];

    f32x16 acc;
#pragma unroll
    for (int r = 0; r < 16; ++r) acc[r] = 0.f;
    float m = -INFINITY, sum = 0.f;

    int skey = tid >> 2, sdg = (tid & 3) * 4;

    for (int c0 = 0; c0 < 2048; c0 += 64) {
        __syncthreads();
        short4v vv = *(const short4v*)&vs[base + (size_t)(c0 + skey) * 16 + sdg];
#pragma unroll
        for (int j = 0; j < 4; ++j) {
            int d = sdg + j;
            vt[(d * 64 + skey) ^ ((d & 7) << 3)] = vv[j];
        }
        __syncthreads();
#pragma unroll
        for (int sub = 0; sub < 2; ++sub) {
            int krow = c0 + sub * 32 + l31;
            short8 kf = *(const short8*)&ks[base + (size_t)krow * 16 + hi * 8];
            f32x16 zero;
#pragma unroll
            for (int r = 0; r < 16; ++r) zero[r] = 0.f;
            // scores already scaled by 0.25*log2e (folded into Q) -> exp2 domain
            f32x16 s2 = __builtin_amdgcn_mfma_f32_32x32x16_bf16(kf, qf, zero, 0, 0, 0);
            float cmax = s2[0];
#pragma unroll
            for (int r = 1; r < 16; ++r) cmax = fmaxf(cmax, s2[r]);
            cmax = fmaxf(cmax, xhalf(cmax, hi));
            // defer-max: only rescale when chunk max exceeds running max by THR=8 (P <= 2^8)
            bool need = cmax > m + 8.f;
            if (__any(need)) {
                float mnew = need ? cmax : m;
                float fac = __builtin_amdgcn_exp2f(m - mnew);   // 1.0 when !need
                m = mnew;
                sum *= fac;
#pragma unroll
                for (int r = 0; r < 16; ++r) acc[r] *= fac;
            }
            float p[16];
            float psum = 0.f;
#pragma unroll
            for (int r = 0; r < 16; ++r) { p[r] = __builtin_amdgcn_exp2f(s2[r] - m); psum += p[r]; }
            sum += psum + xhalf(psum, hi);
            // P -> bf16 pairs, then half-exchange via permlane32_swap:
            // {u0,u2} = swap(w0,w2): u0 = lo?w0:partner(w2), u2 = lo?partner(w0):w2
            unsigned w[8];
#pragma unroll
            for (int e = 0; e < 8; ++e) {
                unsigned t;
                asm("v_cvt_pk_bf16_f32 %0, %1, %2" : "=v"(t) : "v"(p[2 * e]), "v"(p[2 * e + 1]));
                w[e] = t;
            }
            union { unsigned u[4]; short8 v; } b1, b2;
            {
                auto r0 = __builtin_amdgcn_permlane32_swap((int)w[0], (int)w[2], false, false);
                b1.u[0] = (unsigned)r0[0]; b1.u[2] = (unsigned)r0[1];
                auto r1 = __builtin_amdgcn_permlane32_swap((int)w[1], (int)w[3], false, false);
                b1.u[1] = (unsigned)r1[0]; b1.u[3] = (unsigned)r1[1];
                auto r2 = __builtin_amdgcn_permlane32_swap((int)w[4], (int)w[6], false, false);
                b2.u[0] = (unsigned)r2[0]; b2.u[2] = (unsigned)r2[1];
                auto r3 = __builtin_amdgcn_permlane32_swap((int)w[5], (int)w[7], false, false);
                b2.u[1] = (unsigned)r3[0]; b2.u[3] = (unsigned)r3[1];
            }
            int d = lane & 15;
            int i1 = (d * 64 + sub * 32 + hi * 8) ^ ((d & 7) << 3);
            int i2 = (d * 64 + sub * 32 + 16 + hi * 8) ^ ((d & 7) << 3);
            short8 vf1 = *(const short8*)&vt[i1];
            short8 vf2 = *(const short8*)&vt[i2];
            acc = __builtin_amdgcn_mfma_f32_32x32x16_bf16(vf1, b1.v, acc, 0, 0, 0);
            acc = __builtin_amdgcn_mfma_f32_32x32x16_bf16(vf2, b2.v, acc, 0, 0, 0);
        }
    }
    float inv = 1.f / sum;
    int branch = bh >> 4, bb = (bh >> 3) & 1, h = bh & 7;
    size_t orow = (size_t)branch * 4096 + (size_t)bb * 2048 + qrow;
    unsigned u0 = (unsigned)f2bu(acc[0] * inv) | ((unsigned)f2bu(acc[1] * inv) << 16);
    unsigned u1 = (unsigned)f2bu(acc[2] * inv) | ((unsigned)f2bu(acc[3] * inv) << 16);
    unsigned u2 = (unsigned)f2bu(acc[4] * inv) | ((unsigned)f2bu(acc[5] * inv) << 16);
    unsigned u3 = (unsigned)f2bu(acc[6] * inv) | ((unsigned)f2bu(acc[7] * inv) << 16);
    short* op = (short*)o;
    int2v w01; w01.x = (int)u0; w01.y = (int)u1;
    int2v w23; w23.x = (int)u2; w23.y = (int)u3;
    *(int2v*)&op[orow * 128 + h * 16 + 4 * hi] = w01;
    *(int2v*)&op[orow * 128 + h * 16 + 8 + 4 * hi] = w23;
}

// ================= K4: proj GEMM (MFMA) + bias + residual -> xc[4096][384] fp32 =================
__global__ __launch_bounds__(256) void k_proj_m(const bf16* __restrict__ ob, const bf16* __restrict__ wt,
                                                const float* __restrict__ pb, const float* __restrict__ x1,
                                                const float* __restrict__ x2, const float* __restrict__ x3,
                                                float* __restrict__ xc) {
    __shared__ short als[64 * 64];
    __shared__ short wls[64 * 64];
    int branch = blockIdx.z;
    const short* A = (const short*)ob + (size_t)branch * 4096 * 128;
    const short* W = (const short*)wt + (size_t)branch * 128 * 128;
    int rowbase = blockIdx.x * 64, colbase = blockIdx.y * 64;
    f32x16 acc = gemm_tile(A, W, 128, rowbase, colbase, als, wls);
    int tid = threadIdx.x, wid = tid >> 6, lane = tid & 63;
    int hi = lane >> 5, l31 = lane & 31;
    int wm = wid >> 1, wn = wid & 1;
    int c = colbase + wn * 32 + l31;        // 0..127
    float bias = pb[branch * 128 + c];
    const float* xp = (branch == 0) ? x1 : (branch == 1 ? x2 : x3);
#pragma unroll
    for (int i = 0; i < 16; ++i) {
        int mrow = (i & 3) + 8 * (i >> 2) + 4 * hi;
        int row = rowbase + wm * 32 + mrow;
        xc[(size_t)row * 384 + branch * 128 + c] = acc[i] + bias + xp[(size_t)row * 128 + c];
    }
}

// ================= K5: LN2 over 384 features =================
__global__ __launch_bounds__(256) void k_ln2(const float* __restrict__ xc, const float* __restrict__ g,
                                             const float* __restrict__ b, bf16* __restrict__ xcn) {
    int tid = threadIdx.x, wave = tid >> 6, lane = tid & 63;
    int row = blockIdx.x * 4 + wave;  // 0..4095
    const float* rp = xc + (size_t)row * 384;
    float v[6];
    float s = 0.f, sq = 0.f;
#pragma unroll
    for (int i = 0; i < 6; ++i) {
        v[i] = rp[lane + i * 64];
        s += v[i]; sq += v[i] * v[i];
    }
#pragma unroll
    for (int off = 32; off >= 1; off >>= 1) { s += __shfl_xor(s, off); sq += __shfl_xor(sq, off); }
    float mean = s * (1.f / 384.f);
    float var = sq * (1.f / 384.f) - mean * mean;
    float rstd = rsqrtf(var + 1e-5f);
    bf16* op = xcn + (size_t)row * 384;
#pragma unroll
    for (int i = 0; i < 6; ++i) {
        int c = lane + i * 64;
        op[c] = f2b((v[i] - mean) * rstd * g[c] + b[c]);
    }
}

// ================= K6: FC1 GEMM (MFMA) + bias + exact GELU -> h bf16 =================
__global__ __launch_bounds__(256) void k_fc1_m(const bf16* __restrict__ xcn, const bf16* __restrict__ wt,
                                               const float* __restrict__ bias, bf16* __restrict__ h) {
    __shared__ short als[64 * 64];
    __shared__ short wls[64 * 64];
    const short* A = (const short*)xcn;
    const short* W = (const short*)wt;
    int rowbase = blockIdx.x * 64, colbase = blockIdx.y * 64;
    f32x16 acc = gemm_tile(A, W, 384, rowbase, colbase, als, wls);
    int tid = threadIdx.x, wid = tid >> 6, lane = tid & 63;
    int hi = lane >> 5, l31 = lane & 31;
    int wm = wid >> 1, wn = wid & 1;
    int c = colbase + wn * 32 + l31;        // 0..767
    float bs = bias[c];
#pragma unroll
    for (int i = 0; i < 16; ++i) {
        int mrow = (i & 3) + 8 * (i >> 2) + 4 * hi;
        int row = rowbase + wm * 32 + mrow;
        float vv = acc[i] + bs;
        float ge = 0.5f * vv * (1.f + erff(vv * 0.70710678118f));
        h[(size_t)row * 768 + c] = f2b(ge);
    }
}

// ================= K7: FC2 GEMM (MFMA) + bias + residual -> split fp32 outputs =================
__global__ __launch_bounds__(256) void k_fc2_m(const bf16* __restrict__ h, const bf16* __restrict__ wt,
                                               const float* __restrict__ bias, const float* __restrict__ xc,
                                               float* __restrict__ outp) {
    __shared__ short als[64 * 64];
    __shared__ short wls[64 * 64];
    const short* A = (const short*)h;
    const short* W = (const short*)wt;
    int rowbase = blockIdx.x * 64, colbase = blockIdx.y * 64;
    f32x16 acc = gemm_tile(A, W, 768, rowbase, colbase, als, wls);
    int tid = threadIdx.x, wid = tid >> 6, lane = tid & 63;
    int hi = lane >> 5, l31 = lane & 31;
    int wm = wid >> 1, wn = wid & 1;
    int c = colbase + wn * 32 + l31;        // 0..383
    float bs = bias[c];
    int which = c >> 7, cc = c & 127;
#pragma unroll
    for (int i = 0; i < 16; ++i) {
        int mrow = (i & 3) + 8 * (i >> 2) + 4 * hi;
        int row = rowbase + wm * 32 + mrow;
        outp[(size_t)which * 524288 + (size_t)row * 128 + cc] = acc[i] + bs + xc[(size_t)row * 384 + c];
    }
}

// ================= launch =================
extern "C" void kernel_launch(void* const* d_in, const int* in_sizes, int n_in,
                              void* d_out, int out_size, void* d_ws, size_t ws_size,
                              hipStream_t stream) {
    const float* x1     = (const float*)d_in[0];
    const float* x2     = (const float*)d_in[1];
    const float* x3     = (const float*)d_in[2];
    const float* ln1_g  = (const float*)d_in[3];
    const float* ln1_b  = (const float*)d_in[4];
    const float* qkv_w  = (const float*)d_in[5];
    const float* proj_w = (const float*)d_in[6];
    const float* proj_b = (const float*)d_in[7];
    const float* ln2_g  = (const float*)d_in[8];
    const float* ln2_b  = (const float*)d_in[9];
    const float* fc1_w  = (const float*)d_in[10];
    const float* fc1_b  = (const float*)d_in[11];
    const float* fc2_w  = (const float*)d_in[12];
    const float* fc2_b  = (const float*)d_in[13];

    char* ws = (char*)d_ws;
    const size_t SB = 3145728;  // bf16 buffer of 1.5M elems
    bf16* xn  = (bf16*)(ws + 0 * SB);
    bf16* qb  = (bf16*)(ws + 1 * SB);
    bf16* kb  = (bf16*)(ws + 2 * SB);
    bf16* vb  = (bf16*)(ws + 3 * SB);
    bf16* ob  = (bf16*)(ws + 4 * SB);
    float* xc = (float*)(ws + 5 * SB);            // 4096*384*4 = 6291456 B
    bf16* xcn = (bf16*)(ws + 5 * SB + 6291456);   // 3145728 B
    bf16* hb  = (bf16*)(ws + 6 * SB + 6291456);   // 4096*768*2 = 6291456 B
    char* wbase = ws + 31457280;
    bf16* wtq = (bf16*)(wbase);                   // 3*384*128*2 = 294912
    bf16* wtp = (bf16*)(wbase + 294912);          // 3*128*128*2 = 98304
    bf16* wt1 = (bf16*)(wbase + 393216);          // 768*384*2   = 589824
    bf16* wt2 = (bf16*)(wbase + 983040);          // 384*768*2   = 589824
    // total = 33030144 B (~31.5 MB)

    k_wt_all<<<3072, 256, 0, stream>>>(qkv_w, proj_w, fc1_w, fc2_w, wtq, wtp, wt1, wt2);
    k_ln1<<<3072, 256, 0, stream>>>(x1, x2, x3, ln1_g, ln1_b, xn);
    k_qkv_m<<<dim3(64, 6, 3), 256, 0, stream>>>(xn, wtq, qb, kb, vb);
    k_attn<<<dim3(48, 16), 256, 0, stream>>>(qb, kb, vb, ob);
    k_proj_m<<<dim3(64, 2, 3), 256, 0, stream>>>(ob, wtp, proj_b, x1, x2, x3, xc);
    k_ln2<<<1024, 256, 0, stream>>>(xc, ln2_g, ln2_b, xcn);
    k_fc1_m<<<dim3(64, 12, 1), 256, 0, stream>>>(xcn, wt1, fc1_b, hb);
    k_fc2_m<<<dim3(64, 6, 1), 256, 0, stream>>>(hb, wt2, fc2_b, xc, (float*)d_out);
}

// Round 7
// 103.192 us; speedup vs baseline: 10.0475x; 1.0854x over previous
//
#include <hip/hip_runtime.h>
#include <hip/hip_bf16.h>

typedef __hip_bfloat16 bf16;

// ---------- constants ----------
// B=2, N=2048, C=128, H=8, hd=16, branches=3, hid=768
// rows per branch = B*N = 4096; 3C = 384
// I/O fp32; intermediates bf16 except xc (fp32 residual). Weights pre-transposed
// to bf16 Wt[N][K] by k_wt_all. Q is pre-scaled by 0.25*log2e so attention
// softmax runs in the exp2 domain with no per-score scaling.

static __device__ __forceinline__ float b2f(bf16 h) { return __bfloat162float(h); }
static __device__ __forceinline__ bf16 f2b(float f) { return __float2bfloat16(f); }
static __device__ __forceinline__ unsigned short f2bu(float f) {
    bf16 h = f2b(f);
    return *reinterpret_cast<unsigned short*>(&h);
}

typedef __attribute__((ext_vector_type(8))) short short8;
typedef __attribute__((ext_vector_type(4))) short short4v;
typedef __attribute__((ext_vector_type(16))) float f32x16;
typedef __attribute__((ext_vector_type(2))) int int2v;

#define QSCALE 0.36067376022224085f  // 0.25 * log2(e)

// partner-half exchange via permlane32_swap (VALU)
static __device__ __forceinline__ float xhalf(float x, int hi) {
    auto r = __builtin_amdgcn_permlane32_swap(__float_as_int(x), __float_as_int(x), false, false);
    return __int_as_float(hi ? r[0] : r[1]);
}

// ================= K0: all weight transposes+convert in one launch =================
__global__ __launch_bounds__(256) void k_wt_all(const float* __restrict__ qkv_w, const float* __restrict__ proj_w,
                                                const float* __restrict__ fc1_w, const float* __restrict__ fc2_w,
                                                bf16* __restrict__ wtq, bf16* __restrict__ wtp,
                                                bf16* __restrict__ wt1, bf16* __restrict__ wt2) {
    int idx = blockIdx.x * 256 + threadIdx.x;   // < 786432
    if (idx < 147456) {
        int b = idx / 49152, i2 = idx % 49152;
        int n = i2 >> 7, k = i2 & 127;
        wtq[idx] = f2b(qkv_w[b * 49152 + k * 384 + n]);
    } else if (idx < 196608) {
        int j = idx - 147456;
        int b = j / 16384, i2 = j % 16384;
        int n = i2 >> 7, k = i2 & 127;
        wtp[j] = f2b(proj_w[b * 16384 + k * 128 + n]);
    } else if (idx < 491520) {
        int j = idx - 196608;
        int n = j / 384, k = j - n * 384;
        wt1[j] = f2b(fc1_w[k * 768 + n]);
    } else {
        int j = idx - 491520;
        int n = j / 768, k = j - n * 768;
        wt2[j] = f2b(fc2_w[k * 384 + n]);
    }
}

// ================= shared MFMA GEMM tile: C64x64 = A[M,K] . Wt[N,K]^T =================
__device__ __forceinline__ f32x16 gemm_tile(const short* __restrict__ A, const short* __restrict__ W,
                                            int K, int rowbase, int colbase,
                                            short* als, short* wls) {
    int tid = threadIdx.x;
    int wid = tid >> 6, lane = tid & 63;
    int hi = lane >> 5, l31 = lane & 31;
    int wm = wid >> 1, wn = wid & 1;
    int sr = tid >> 3, skb = tid & 7;   // staging: row (0..31), k-block (0..7)
    f32x16 acc;
#pragma unroll
    for (int i = 0; i < 16; ++i) acc[i] = 0.f;
    for (int k0 = 0; k0 < K; k0 += 64) {
        __syncthreads();
#pragma unroll
        for (int pass = 0; pass < 2; ++pass) {
            int r = sr + pass * 32;
            short8 av = *(const short8*)&A[(size_t)(rowbase + r) * K + k0 + skb * 8];
            *(short8*)&als[r * 64 + ((skb ^ (r & 7)) * 8)] = av;
            short8 wv = *(const short8*)&W[(size_t)(colbase + r) * K + k0 + skb * 8];
            *(short8*)&wls[r * 64 + ((skb ^ (r & 7)) * 8)] = wv;
        }
        __syncthreads();
#pragma unroll
        for (int ks = 0; ks < 4; ++ks) {
            int ra = wm * 32 + l31;
            int rb = wn * 32 + l31;
            int kb = ks * 2 + hi;
            short8 af = *(const short8*)&als[ra * 64 + ((kb ^ (ra & 7)) * 8)];
            short8 bf = *(const short8*)&wls[rb * 64 + ((kb ^ (rb & 7)) * 8)];
            acc = __builtin_amdgcn_mfma_f32_32x32x16_bf16(af, bf, acc, 0, 0, 0);
        }
    }
    return acc;
}

// ================= K1: LN1 for all 3 branches =================
__global__ __launch_bounds__(256) void k_ln1(const float* __restrict__ x1, const float* __restrict__ x2,
                                             const float* __restrict__ x3, const float* __restrict__ g,
                                             const float* __restrict__ b, bf16* __restrict__ xn) {
    int tid = threadIdx.x;
    int wave = tid >> 6, lane = tid & 63;
    int grow = blockIdx.x * 4 + wave;      // 0..12287
    int branch = grow >> 12;
    const float* xp = (branch == 0) ? x1 : (branch == 1 ? x2 : x3);
    const float* row = xp + (size_t)(grow & 4095) * 128;
    float2 a = *reinterpret_cast<const float2*>(&row[2 * lane]);
    float s = a.x + a.y, sq = a.x * a.x + a.y * a.y;
#pragma unroll
    for (int off = 32; off >= 1; off >>= 1) { s += __shfl_xor(s, off); sq += __shfl_xor(sq, off); }
    float mean = s * (1.f / 128.f);
    float var = sq * (1.f / 128.f) - mean * mean;
    float rstd = rsqrtf(var + 1e-5f);
    float2 gv = *reinterpret_cast<const float2*>(&g[branch * 128 + 2 * lane]);
    float2 bv = *reinterpret_cast<const float2*>(&b[branch * 128 + 2 * lane]);
    bf16* orow = xn + (size_t)grow * 128;
    orow[2 * lane] = f2b((a.x - mean) * rstd * gv.x + bv.x);
    orow[2 * lane + 1] = f2b((a.y - mean) * rstd * gv.y + bv.y);
}

// ================= K2: QKV GEMM (MFMA) + scatter to q/k/v head layout (Q pre-scaled) =================
__global__ __launch_bounds__(256) void k_qkv_m(const bf16* __restrict__ xn, const bf16* __restrict__ wt,
                                               bf16* __restrict__ q, bf16* __restrict__ k, bf16* __restrict__ v) {
    __shared__ short als[64 * 64];
    __shared__ short wls[64 * 64];
    int branch = blockIdx.z;
    const short* A = (const short*)xn + (size_t)branch * 4096 * 128;
    const short* W = (const short*)wt + (size_t)branch * 384 * 128;
    int rowbase = blockIdx.x * 64, colbase = blockIdx.y * 64;
    f32x16 acc = gemm_tile(A, W, 128, rowbase, colbase, als, wls);
    int tid = threadIdx.x, wid = tid >> 6, lane = tid & 63;
    int hi = lane >> 5, l31 = lane & 31;
    int wm = wid >> 1, wn = wid & 1;
    int c = colbase + wn * 32 + l31;        // 0..383
    int which = c >> 7, h = (c >> 4) & 7, d = c & 15;
    bf16* dst = (which == 0) ? q : (which == 1 ? k : v);
    float scl = (which == 0) ? QSCALE : 1.0f;
#pragma unroll
    for (int i = 0; i < 16; ++i) {
        int mrow = (i & 3) + 8 * (i >> 2) + 4 * hi;
        int token = rowbase + wm * 32 + mrow;
        int bb = token >> 11, n = token & 2047;
        dst[((((size_t)branch * 2 + bb) * 8 + h) * 2048 + n) * 16 + d] = f2b(acc[i] * scl);
    }
}

// ================= K3: MFMA attention — speculative-exp flash =================
// 128 threads = 2 waves; wave owns 32 q-rows; grid (48 bh, 32 qblk) = 1536 blocks.
// Fast path per 64 keys: 2 QK^T MFMA (C = -m broadcast) -> 32 exp2 -> psum ->
// threshold check -> cvt_pk/permlane -> 4 PV MFMA. No max-reduce, no cross-lane
// in fast path. Slow path (psum > 256): m += log2(pmax), rescale p/sum/acc.
// V double-buffered in LDS [2][16][64] swizzled; staged with ds_write_b128.
__global__ __launch_bounds__(128, 4) void k_attn(const bf16* __restrict__ qg, const bf16* __restrict__ kg,
                                                 const bf16* __restrict__ vg, bf16* __restrict__ o) {
    __shared__ short vt[2][16 * 64];
    int bh = blockIdx.x;            // (branch*2+b)*8+h
    int qblk = blockIdx.y;          // 0..31
    size_t base = (size_t)bh * (2048 * 16);
    int tid = threadIdx.x, wave = tid >> 6, lane = tid & 63;
    int hi = lane >> 5, l31 = lane & 31;
    int qrow = qblk * 64 + wave * 32 + l31;
    const short* qs = (const short*)qg;
    const short* ks = (const short*)kg;
    const short* vs = (const short*)vg;
    short8 qf = *(const short8*)&qs[base + (size_t)qrow * 16 + hi * 8];

    f32x16 acc;
    f32x16 negm;
#pragma unroll
    for (int r = 0; r < 16; ++r) { acc[r] = 0.f; negm[r] = -16.f; }
    float m = 16.f, sum = 0.f;

    int sd = tid & 15, sk0 = (tid >> 4) * 8;   // staging: d row, 8 consecutive keys
    int swzs = (sd & 7) << 3;

    // prologue: stage chunk 0
    {
        short va[8];
#pragma unroll
        for (int j = 0; j < 8; ++j) va[j] = vs[base + (size_t)(sk0 + j) * 16 + sd];
        short8 wv;
#pragma unroll
        for (int j = 0; j < 8; ++j) wv[j] = va[j];
        *(short8*)&vt[0][sd * 64 + (sk0 ^ swzs)] = wv;
    }
    __syncthreads();

    for (int c0 = 0; c0 < 2048; c0 += 64) {
        int cur = (c0 >> 6) & 1;
        bool more = (c0 + 64) < 2048;
        // K fragments for current chunk + V prefetch for next chunk
        short8 kf0 = *(const short8*)&ks[base + (size_t)(c0 + l31) * 16 + hi * 8];
        short8 kf1 = *(const short8*)&ks[base + (size_t)(c0 + 32 + l31) * 16 + hi * 8];
        short va[8];
        if (more) {
#pragma unroll
            for (int j = 0; j < 8; ++j) va[j] = vs[base + (size_t)(c0 + 64 + sk0 + j) * 16 + sd];
        }
        // QK^T with -m folded into C: output = s - m (exp2 domain)
        f32x16 pa = __builtin_amdgcn_mfma_f32_32x32x16_bf16(kf0, qf, negm, 0, 0, 0);
        f32x16 pb = __builtin_amdgcn_mfma_f32_32x32x16_bf16(kf1, qf, negm, 0, 0, 0);
        // speculative exp2 (no max reduce)
#pragma unroll
        for (int r = 0; r < 16; ++r) pa[r] = __builtin_amdgcn_exp2f(pa[r]);
#pragma unroll
        for (int r = 0; r < 16; ++r) pb[r] = __builtin_amdgcn_exp2f(pb[r]);
        float e0 = 0.f, e1 = 0.f, e2 = 0.f, e3 = 0.f;
#pragma unroll
        for (int r = 0; r < 16; r += 4) { e0 += pa[r]; e1 += pa[r + 1]; e2 += pa[r + 2]; e3 += pa[r + 3]; }
#pragma unroll
        for (int r = 0; r < 16; r += 4) { e0 += pb[r]; e1 += pb[r + 1]; e2 += pb[r + 2]; e3 += pb[r + 3]; }
        float psum = (e0 + e1) + (e2 + e3);
        if (__any(psum > 256.f)) {
            // slow path: recover chunk max from p, bump m, rescale
            float p0 = fmaxf(pa[0], pa[1]), p1 = fmaxf(pa[2], pa[3]);
#pragma unroll
            for (int r = 4; r < 16; r += 4) { p0 = fmaxf(p0, fmaxf(pa[r], pa[r + 1])); p1 = fmaxf(p1, fmaxf(pa[r + 2], pa[r + 3])); }
#pragma unroll
            for (int r = 0; r < 16; r += 4) { p0 = fmaxf(p0, fmaxf(pb[r], pb[r + 1])); p1 = fmaxf(p1, fmaxf(pb[r + 2], pb[r + 3])); }
            float pmax = fmaxf(p0, p1);
            pmax = fmaxf(pmax, xhalf(pmax, hi));
            float delta = fmaxf(0.f, __log2f(pmax));
            float fac = __builtin_amdgcn_exp2f(-delta);
            m += delta;
#pragma unroll
            for (int r = 0; r < 16; ++r) negm[r] = -m;
            sum *= fac; psum *= fac;
#pragma unroll
            for (int r = 0; r < 16; ++r) { pa[r] *= fac; pb[r] *= fac; acc[r] *= fac; }
        }
        sum += psum;
        // P -> bf16 pairs, half-exchange via permlane32_swap
        unsigned wa[8], wb[8];
#pragma unroll
        for (int e = 0; e < 8; ++e) {
            unsigned t;
            asm("v_cvt_pk_bf16_f32 %0, %1, %2" : "=v"(t) : "v"(pa[2 * e]), "v"(pa[2 * e + 1]));
            wa[e] = t;
            asm("v_cvt_pk_bf16_f32 %0, %1, %2" : "=v"(t) : "v"(pb[2 * e]), "v"(pb[2 * e + 1]));
            wb[e] = t;
        }
        union { unsigned u[4]; short8 v; } b1, b2, b3, b4;
        {
            auto r0 = __builtin_amdgcn_permlane32_swap((int)wa[0], (int)wa[2], false, false);
            b1.u[0] = (unsigned)r0[0]; b1.u[2] = (unsigned)r0[1];
            auto r1 = __builtin_amdgcn_permlane32_swap((int)wa[1], (int)wa[3], false, false);
            b1.u[1] = (unsigned)r1[0]; b1.u[3] = (unsigned)r1[1];
            auto r2 = __builtin_amdgcn_permlane32_swap((int)wa[4], (int)wa[6], false, false);
            b2.u[0] = (unsigned)r2[0]; b2.u[2] = (unsigned)r2[1];
            auto r3 = __builtin_amdgcn_permlane32_swap((int)wa[5], (int)wa[7], false, false);
            b2.u[1] = (unsigned)r3[0]; b2.u[3] = (unsigned)r3[1];
            auto r4 = __builtin_amdgcn_permlane32_swap((int)wb[0], (int)wb[2], false, false);
            b3.u[0] = (unsigned)r4[0]; b3.u[2] = (unsigned)r4[1];
            auto r5 = __builtin_amdgcn_permlane32_swap((int)wb[1], (int)wb[3], false, false);
            b3.u[1] = (unsigned)r5[0]; b3.u[3] = (unsigned)r5[1];
            auto r6 = __builtin_amdgcn_permlane32_swap((int)wb[4], (int)wb[6], false, false);
            b4.u[0] = (unsigned)r6[0]; b4.u[2] = (unsigned)r6[1];
            auto r7 = __builtin_amdgcn_permlane32_swap((int)wb[5], (int)wb[7], false, false);
            b4.u[1] = (unsigned)r7[0]; b4.u[3] = (unsigned)r7[1];
        }
        // PV: O^T += V^T . P^T (4 k-slices of 16 keys)
        int d = lane & 15;
        short8 vf;
        vf = *(const short8*)&vt[cur][(d * 64 + hi * 8) ^ ((d & 7) << 3)];
        acc = __builtin_amdgcn_mfma_f32_32x32x16_bf16(vf, b1.v, acc, 0, 0, 0);
        vf = *(const short8*)&vt[cur][(d * 64 + 16 + hi * 8) ^ ((d & 7) << 3)];
        acc = __builtin_amdgcn_mfma_f32_32x32x16_bf16(vf, b2.v, acc, 0, 0, 0);
        vf = *(const short8*)&vt[cur][(d * 64 + 32 + hi * 8) ^ ((d & 7) << 3)];
        acc = __builtin_amdgcn_mfma_f32_32x32x16_bf16(vf, b3.v, acc, 0, 0, 0);
        vf = *(const short8*)&vt[cur][(d * 64 + 48 + hi * 8) ^ ((d & 7) << 3)];
        acc = __builtin_amdgcn_mfma_f32_32x32x16_bf16(vf, b4.v, acc, 0, 0, 0);
        // stage next chunk into the other buffer
        if (more) {
            short8 wv;
#pragma unroll
            for (int j = 0; j < 8; ++j) wv[j] = va[j];
            *(short8*)&vt[cur ^ 1][sd * 64 + (sk0 ^ swzs)] = wv;
        }
        __syncthreads();
    }
    // epilogue: combine per-half sums; regs 0..7 hold O^T rows d
    sum += xhalf(sum, hi);
    float inv = 1.f / sum;
    int branch = bh >> 4, bb = (bh >> 3) & 1, h = bh & 7;
    size_t orow = (size_t)branch * 4096 + (size_t)bb * 2048 + qrow;
    unsigned u0 = (unsigned)f2bu(acc[0] * inv) | ((unsigned)f2bu(acc[1] * inv) << 16);
    unsigned u1 = (unsigned)f2bu(acc[2] * inv) | ((unsigned)f2bu(acc[3] * inv) << 16);
    unsigned u2 = (unsigned)f2bu(acc[4] * inv) | ((unsigned)f2bu(acc[5] * inv) << 16);
    unsigned u3 = (unsigned)f2bu(acc[6] * inv) | ((unsigned)f2bu(acc[7] * inv) << 16);
    short* op = (short*)o;
    int2v w01; w01.x = (int)u0; w01.y = (int)u1;
    int2v w23; w23.x = (int)u2; w23.y = (int)u3;
    *(int2v*)&op[orow * 128 + h * 16 + 4 * hi] = w01;
    *(int2v*)&op[orow * 128 + h * 16 + 8 + 4 * hi] = w23;
}

// ================= K4: proj GEMM (MFMA) + bias + residual -> xc[4096][384] fp32 =================
__global__ __launch_bounds__(256) void k_proj_m(const bf16* __restrict__ ob, const bf16* __restrict__ wt,
                                                const float* __restrict__ pb, const float* __restrict__ x1,
                                                const float* __restrict__ x2, const float* __restrict__ x3,
                                                float* __restrict__ xc) {
    __shared__ short als[64 * 64];
    __shared__ short wls[64 * 64];
    int branch = blockIdx.z;
    const short* A = (const short*)ob + (size_t)branch * 4096 * 128;
    const short* W = (const short*)wt + (size_t)branch * 128 * 128;
    int rowbase = blockIdx.x * 64, colbase = blockIdx.y * 64;
    f32x16 acc = gemm_tile(A, W, 128, rowbase, colbase, als, wls);
    int tid = threadIdx.x, wid = tid >> 6, lane = tid & 63;
    int hi = lane >> 5, l31 = lane & 31;
    int wm = wid >> 1, wn = wid & 1;
    int c = colbase + wn * 32 + l31;        // 0..127
    float bias = pb[branch * 128 + c];
    const float* xp = (branch == 0) ? x1 : (branch == 1 ? x2 : x3);
#pragma unroll
    for (int i = 0; i < 16; ++i) {
        int mrow = (i & 3) + 8 * (i >> 2) + 4 * hi;
        int row = rowbase + wm * 32 + mrow;
        xc[(size_t)row * 384 + branch * 128 + c] = acc[i] + bias + xp[(size_t)row * 128 + c];
    }
}

// ================= K5: LN2 over 384 features =================
__global__ __launch_bounds__(256) void k_ln2(const float* __restrict__ xc, const float* __restrict__ g,
                                             const float* __restrict__ b, bf16* __restrict__ xcn) {
    int tid = threadIdx.x, wave = tid >> 6, lane = tid & 63;
    int row = blockIdx.x * 4 + wave;  // 0..4095
    const float* rp = xc + (size_t)row * 384;
    float v[6];
    float s = 0.f, sq = 0.f;
#pragma unroll
    for (int i = 0; i < 6; ++i) {
        v[i] = rp[lane + i * 64];
        s += v[i]; sq += v[i] * v[i];
    }
#pragma unroll
    for (int off = 32; off >= 1; off >>= 1) { s += __shfl_xor(s, off); sq += __shfl_xor(sq, off); }
    float mean = s * (1.f / 384.f);
    float var = sq * (1.f / 384.f) - mean * mean;
    float rstd = rsqrtf(var + 1e-5f);
    bf16* op = xcn + (size_t)row * 384;
#pragma unroll
    for (int i = 0; i < 6; ++i) {
        int c = lane + i * 64;
        op[c] = f2b((v[i] - mean) * rstd * g[c] + b[c]);
    }
}

// ================= K6: FC1 GEMM (MFMA) + bias + exact GELU -> h bf16 =================
__global__ __launch_bounds__(256) void k_fc1_m(const bf16* __restrict__ xcn, const bf16* __restrict__ wt,
                                               const float* __restrict__ bias, bf16* __restrict__ h) {
    __shared__ short als[64 * 64];
    __shared__ short wls[64 * 64];
    const short* A = (const short*)xcn;
    const short* W = (const short*)wt;
    int rowbase = blockIdx.x * 64, colbase = blockIdx.y * 64;
    f32x16 acc = gemm_tile(A, W, 384, rowbase, colbase, als, wls);
    int tid = threadIdx.x, wid = tid >> 6, lane = tid & 63;
    int hi = lane >> 5, l31 = lane & 31;
    int wm = wid >> 1, wn = wid & 1;
    int c = colbase + wn * 32 + l31;        // 0..767
    float bs = bias[c];
#pragma unroll
    for (int i = 0; i < 16; ++i) {
        int mrow = (i & 3) + 8 * (i >> 2) + 4 * hi;
        int row = rowbase + wm * 32 + mrow;
        float vv = acc[i] + bs;
        float ge = 0.5f * vv * (1.f + erff(vv * 0.70710678118f));
        h[(size_t)row * 768 + c] = f2b(ge);
    }
}

// ================= K7: FC2 GEMM (MFMA) + bias + residual -> split fp32 outputs =================
__global__ __launch_bounds__(256) void k_fc2_m(const bf16* __restrict__ h, const bf16* __restrict__ wt,
                                               const float* __restrict__ bias, const float* __restrict__ xc,
                                               float* __restrict__ outp) {
    __shared__ short als[64 * 64];
    __shared__ short wls[64 * 64];
    const short* A = (const short*)h;
    const short* W = (const short*)wt;
    int rowbase = blockIdx.x * 64, colbase = blockIdx.y * 64;
    f32x16 acc = gemm_tile(A, W, 768, rowbase, colbase, als, wls);
    int tid = threadIdx.x, wid = tid >> 6, lane = tid & 63;
    int hi = lane >> 5, l31 = lane & 31;
    int wm = wid >> 1, wn = wid & 1;
    int c = colbase + wn * 32 + l31;        // 0..383
    float bs = bias[c];
    int which = c >> 7, cc = c & 127;
#pragma unroll
    for (int i = 0; i < 16; ++i) {
        int mrow = (i & 3) + 8 * (i >> 2) + 4 * hi;
        int row = rowbase + wm * 32 + mrow;
        outp[(size_t)which * 524288 + (size_t)row * 128 + cc] = acc[i] + bs + xc[(size_t)row * 384 + c];
    }
}

// ================= launch =================
extern "C" void kernel_launch(void* const* d_in, const int* in_sizes, int n_in,
                              void* d_out, int out_size, void* d_ws, size_t ws_size,
                              hipStream_t stream) {
    const float* x1     = (const float*)d_in[0];
    const float* x2     = (const float*)d_in[1];
    const float* x3     = (const float*)d_in[2];
    const float* ln1_g  = (const float*)d_in[3];
    const float* ln1_b  = (const float*)d_in[4];
    const float* qkv_w  = (const float*)d_in[5];
    const float* proj_w = (const float*)d_in[6];
    const float* proj_b = (const float*)d_in[7];
    const float* ln2_g  = (const float*)d_in[8];
    const float* ln2_b  = (const float*)d_in[9];
    const float* fc1_w  = (const float*)d_in[10];
    const float* fc1_b  = (const float*)d_in[11];
    const float* fc2_w  = (const float*)d_in[12];
    const float* fc2_b  = (const float*)d_in[13];

    char* ws = (char*)d_ws;
    const size_t SB = 3145728;  // bf16 buffer of 1.5M elems
    bf16* xn  = (bf16*)(ws + 0 * SB);
    bf16* qb  = (bf16*)(ws + 1 * SB);
    bf16* kb  = (bf16*)(ws + 2 * SB);
    bf16* vb  = (bf16*)(ws + 3 * SB);
    bf16* ob  = (bf16*)(ws + 4 * SB);
    float* xc = (float*)(ws + 5 * SB);            // 4096*384*4 = 6291456 B
    bf16* xcn = (bf16*)(ws + 5 * SB + 6291456);   // 3145728 B
    bf16* hb  = (bf16*)(ws + 6 * SB + 6291456);   // 4096*768*2 = 6291456 B
    char* wbase = ws + 31457280;
    bf16* wtq = (bf16*)(wbase);                   // 3*384*128*2 = 294912
    bf16* wtp = (bf16*)(wbase + 294912);          // 3*128*128*2 = 98304
    bf16* wt1 = (bf16*)(wbase + 393216);          // 768*384*2   = 589824
    bf16* wt2 = (bf16*)(wbase + 983040);          // 384*768*2   = 589824
    // total = 33030144 B (~31.5 MB)

    k_wt_all<<<3072, 256, 0, stream>>>(qkv_w, proj_w, fc1_w, fc2_w, wtq, wtp, wt1, wt2);
    k_ln1<<<3072, 256, 0, stream>>>(x1, x2, x3, ln1_g, ln1_b, xn);
    k_qkv_m<<<dim3(64, 6, 3), 256, 0, stream>>>(xn, wtq, qb, kb, vb);
    k_attn<<<dim3(48, 32), 128, 0, stream>>>(qb, kb, vb, ob);
    k_proj_m<<<dim3(64, 2, 3), 256, 0, stream>>>(ob, wtp, proj_b, x1, x2, x3, xc);
    k_ln2<<<1024, 256, 0, stream>>>(xc, ln2_g, ln2_b, xcn);
    k_fc1_m<<<dim3(64, 12, 1), 256, 0, stream>>>(xcn, wt1, fc1_b, hb);
    k_fc2_m<<<dim3(64, 6, 1), 256, 0, stream>>>(hb, wt2, fc2_b, xc, (float*)d_out);
}